// Round 11
// baseline (238.542 us; speedup 1.0000x reference)
//
#include <hip/hip_runtime.h>
#include <hip/hip_bf16.h>
#include <cstdint>

#define BDIM 768
#define HN 12
#define HDIM 64
#define SEQ 2048
#define BATCH 4
#define MTOT (BATCH * SEQ)     // 8192

typedef __attribute__((ext_vector_type(8))) short bfrag;   // 8 bf16 (4 VGPR)
typedef __attribute__((ext_vector_type(4))) float f32x4;

union pfu { bfrag f; unsigned u[4]; };

static __device__ __forceinline__ unsigned short f2bf(float f) {
    union { float f; unsigned u; } v; v.f = f;
    unsigned r = v.u + 0x7FFF + ((v.u >> 16) & 1);   // RNE
    return (unsigned short)(r >> 16);
}

static __device__ __forceinline__ float fexp2(float x) {
    float r; asm("v_exp_f32 %0, %1" : "=v"(r) : "v"(x)); return r;
}

static __device__ __forceinline__ unsigned cvt_pk_bf16(float lo, float hi) {
    unsigned r;
    asm("v_cvt_pk_bf16_f32 %0, %1, %2" : "=v"(r) : "v"(lo), "v"(hi));
    return r;
}

// ---- cross-lane helpers: permlane swaps (VALU) with shfl fallback ----------
#if __has_builtin(__builtin_amdgcn_permlane32_swap) && __has_builtin(__builtin_amdgcn_permlane16_swap)
#define HAVE_PERMLANE 1
#else
#define HAVE_PERMLANE 0
#endif

static __device__ __forceinline__ float redmax16(float x) {
#if HAVE_PERMLANE
    union { float f; unsigned u; } a; a.f = x;
    auto r = __builtin_amdgcn_permlane16_swap(a.u, a.u, false, false);
    union { unsigned u; float f; } p, q; p.u = r[0]; q.u = r[1];
    return fmaxf(p.f, q.f);
#else
    return fmaxf(x, __shfl_xor(x, 16));
#endif
}

static __device__ __forceinline__ float redmax32(float x) {
#if HAVE_PERMLANE
    union { float f; unsigned u; } a; a.f = x;
    auto r = __builtin_amdgcn_permlane32_swap(a.u, a.u, false, false);
    union { unsigned u; float f; } p, q; p.u = r[0]; q.u = r[1];
    return fmaxf(p.f, q.f);
#else
    return fmaxf(x, __shfl_xor(x, 32));
#endif
}

// ---------------- prep: fp32 -> bf16 flat convert (+ queue init) -------------
__global__ __launch_bounds__(256) void conv_f32_bf16(
    const float* __restrict__ in, unsigned short* __restrict__ out, int n8,
    int* __restrict__ qctr)
{
    if (blockIdx.x == 0 && threadIdx.x < 8) qctr[threadIdx.x] = 0;
    const int i = blockIdx.x * 256 + threadIdx.x;
    if (i >= n8) return;
    const float4 a = ((const float4*)in)[i * 2];
    const float4 b = ((const float4*)in)[i * 2 + 1];
    bfrag o;
    o[0] = f2bf(a.x); o[1] = f2bf(a.y); o[2] = f2bf(a.z); o[3] = f2bf(a.w);
    o[4] = f2bf(b.x); o[5] = f2bf(b.y); o[6] = f2bf(b.z); o[7] = f2bf(b.w);
    ((bfrag*)out)[i] = o;
}

// ---------------- prep: [R][C] fp32 -> [C][R] bf16 transpose ----------------
__global__ __launch_bounds__(256) void transpose_f32_bf16(
    const float* __restrict__ in, unsigned short* __restrict__ out, int R, int C)
{
    __shared__ unsigned short t[64][72];
    const int tid = threadIdx.x;
    const int c0 = blockIdx.x * 64, r0 = blockIdx.y * 64;
    #pragma unroll
    for (int i = 0; i < 4; ++i) {
        const int r = (tid >> 4) + i * 16;
        const int c = (tid & 15) * 4;
        const float4 v = *(const float4*)&in[(size_t)(r0 + r) * C + c0 + c];
        t[c + 0][r] = f2bf(v.x);
        t[c + 1][r] = f2bf(v.y);
        t[c + 2][r] = f2bf(v.z);
        t[c + 3][r] = f2bf(v.w);
    }
    __syncthreads();
    #pragma unroll
    for (int i = 0; i < 2; ++i) {
        const int c = (tid >> 3) + i * 32;
        const int r = (tid & 7) * 8;
        *(bfrag*)&out[(size_t)(c0 + c) * R + r0 + r] = *(const bfrag*)&t[c][r];
    }
}

// ---------------- GEMM1: qkv = x @ wqT^T + b, routed to qb/kb/vT ------------
__global__ __launch_bounds__(256) void gemm_qkv(
    const unsigned short* __restrict__ A,
    const unsigned short* __restrict__ Bt,
    const float* __restrict__ bias,
    unsigned short* __restrict__ qb,
    unsigned short* __restrict__ kb,
    unsigned short* __restrict__ vTt)
{
    __shared__ unsigned short As[128 * 64];
    __shared__ unsigned short Bs[128 * 64];

    const int tid  = threadIdx.x;
    const int lane = tid & 63;
    const int wid  = tid >> 6;
    const int l15  = lane & 15;
    const int l4   = lane >> 4;
    const int m0 = blockIdx.y * 128;
    const int n0 = blockIdx.x * 128;
    const int wm = (wid >> 1) * 64;
    const int wn = (wid & 1) * 64;

    f32x4 acc[4][4] = {};

    for (int k0 = 0; k0 < BDIM; k0 += 64) {
        __syncthreads();
        #pragma unroll
        for (int i = 0; i < 4; ++i) {
            const int row = wid * 32 + i * 8 + (lane >> 3);
            const int ck  = (((lane & 7) ^ (row & 7)) * 8);
            __builtin_amdgcn_global_load_lds(
                (const __attribute__((address_space(1))) void*)(A + (size_t)(m0 + row) * BDIM + k0 + ck),
                (__attribute__((address_space(3))) void*)(As + (wid * 4 + i) * 512),
                16, 0, 0);
            __builtin_amdgcn_global_load_lds(
                (const __attribute__((address_space(1))) void*)(Bt + (size_t)(n0 + row) * BDIM + k0 + ck),
                (__attribute__((address_space(3))) void*)(Bs + (wid * 4 + i) * 512),
                16, 0, 0);
        }
        __syncthreads();

        #pragma unroll
        for (int ks = 0; ks < 2; ++ks) {
            bfrag af[4], bfv[4];
            #pragma unroll
            for (int mi = 0; mi < 4; ++mi) {
                const int row = wm + mi * 16 + l15;
                const int ch  = (ks * 4 + l4) ^ (row & 7);
                af[mi] = *(const bfrag*)(As + row * 64 + ch * 8);
            }
            #pragma unroll
            for (int ni = 0; ni < 4; ++ni) {
                const int row = wn + ni * 16 + l15;
                const int ch  = (ks * 4 + l4) ^ (row & 7);
                bfv[ni] = *(const bfrag*)(Bs + row * 64 + ch * 8);
            }
            #pragma unroll
            for (int mi = 0; mi < 4; ++mi)
                #pragma unroll
                for (int ni = 0; ni < 4; ++ni)
                    acc[mi][ni] = __builtin_amdgcn_mfma_f32_16x16x32_bf16(
                        af[mi], bfv[ni], acc[mi][ni], 0, 0, 0);
        }
    }

    const int nb = n0 + wn;
    if (nb < 1536) {
        unsigned short* dst = (nb < 768) ? qb : kb;
        const int coff = (nb < 768) ? 0 : 768;
        #pragma unroll
        for (int mi = 0; mi < 4; ++mi)
            #pragma unroll
            for (int ni = 0; ni < 4; ++ni) {
                const int n = nb + ni * 16 + l15;
                const float bv = bias[n];
                #pragma unroll
                for (int r = 0; r < 4; ++r) {
                    const int m = m0 + wm + mi * 16 + l4 * 4 + r;
                    dst[(size_t)m * BDIM + (n - coff)] = f2bf(acc[mi][ni][r] + bv);
                }
            }
    } else {
        // V block: write transposed into vT[(b*768 + n-1536)][s]
        #pragma unroll
        for (int mi = 0; mi < 4; ++mi)
            #pragma unroll
            for (int ni = 0; ni < 4; ++ni) {
                const int n = nb + ni * 16 + l15;
                const float bv = bias[n];
                const size_t vrow = (size_t)(m0 >> 11) * 768 + (n - 1536);
                const int mbase = m0 + wm + mi * 16 + l4 * 4;
                const int scol = mbase & (SEQ - 1);
                uint2 u2;
                u2.x = (unsigned)f2bf(acc[mi][ni][0] + bv)
                     | ((unsigned)f2bf(acc[mi][ni][1] + bv) << 16);
                u2.y = (unsigned)f2bf(acc[mi][ni][2] + bv)
                     | ((unsigned)f2bf(acc[mi][ni][3] + bv) << 16);
                *(uint2*)(vTt + vrow * SEQ + scol) = u2;
            }
    }
}

// ---------------- GEMM2: out = yatt @ wpT^T + b (fp32 out), 64x128 tiles ----
__global__ __launch_bounds__(256) void gemm_proj(
    const unsigned short* __restrict__ A,   // [8192][768] bf16
    const unsigned short* __restrict__ Bt,  // [768][768] bf16
    const float* __restrict__ bias,
    float* __restrict__ C)
{
    __shared__ unsigned short As[64 * 64];    // 64 M-rows x 64 k
    __shared__ unsigned short Bs[128 * 64];   // 128 N-rows x 64 k

    const int tid  = threadIdx.x;
    const int lane = tid & 63;
    const int wid  = tid >> 6;
    const int l15  = lane & 15;
    const int l4   = lane >> 4;
    const int m0 = blockIdx.y * 64;
    const int n0 = blockIdx.x * 128;
    const int wm = (wid >> 1) * 32;    // 2 m-sub of 32 rows
    const int wn = (wid & 1) * 64;

    f32x4 acc[2][4] = {};

    for (int k0 = 0; k0 < BDIM; k0 += 64) {
        __syncthreads();
        #pragma unroll
        for (int i = 0; i < 2; ++i) {   // A: 64 rows, 2 instr/wave
            const int row = wid * 16 + i * 8 + (lane >> 3);
            const int ck  = (((lane & 7) ^ (row & 7)) * 8);
            __builtin_amdgcn_global_load_lds(
                (const __attribute__((address_space(1))) void*)(A + (size_t)(m0 + row) * BDIM + k0 + ck),
                (__attribute__((address_space(3))) void*)(As + (wid * 16 + i * 8) * 64),
                16, 0, 0);
        }
        #pragma unroll
        for (int i = 0; i < 4; ++i) {   // B: 128 rows, 4 instr/wave
            const int row = wid * 32 + i * 8 + (lane >> 3);
            const int ck  = (((lane & 7) ^ (row & 7)) * 8);
            __builtin_amdgcn_global_load_lds(
                (const __attribute__((address_space(1))) void*)(Bt + (size_t)(n0 + row) * BDIM + k0 + ck),
                (__attribute__((address_space(3))) void*)(Bs + (wid * 32 + i * 8) * 64),
                16, 0, 0);
        }
        __syncthreads();

        #pragma unroll
        for (int ks = 0; ks < 2; ++ks) {
            bfrag af[2], bfv[4];
            #pragma unroll
            for (int mi = 0; mi < 2; ++mi) {
                const int row = wm + mi * 16 + l15;
                const int ch  = (ks * 4 + l4) ^ (row & 7);
                af[mi] = *(const bfrag*)(As + row * 64 + ch * 8);
            }
            #pragma unroll
            for (int ni = 0; ni < 4; ++ni) {
                const int row = wn + ni * 16 + l15;
                const int ch  = (ks * 4 + l4) ^ (row & 7);
                bfv[ni] = *(const bfrag*)(Bs + row * 64 + ch * 8);
            }
            #pragma unroll
            for (int mi = 0; mi < 2; ++mi)
                #pragma unroll
                for (int ni = 0; ni < 4; ++ni)
                    acc[mi][ni] = __builtin_amdgcn_mfma_f32_16x16x32_bf16(
                        af[mi], bfv[ni], acc[mi][ni], 0, 0, 0);
        }
    }

    #pragma unroll
    for (int mi = 0; mi < 2; ++mi)
        #pragma unroll
        for (int ni = 0; ni < 4; ++ni) {
            const int n = n0 + wn + ni * 16 + l15;
            const float bv = bias[n];
            #pragma unroll
            for (int r = 0; r < 4; ++r) {
                const int m = m0 + wm + mi * 16 + l4 * 4 + r;
                C[(size_t)m * BDIM + n] = acc[mi][ni][r] + bv;
            }
        }
}

// ---------------- MFMA flash attention: dual q-half, MFMA row-sum -----------
// Item = (bh, p): q-rows [p*128, p*128+128), K-tiles 0..2p+1. 768 items,
// longest-first, 8 queues x 96; grid 1024 (4 blocks/CU).
#define C2 0.18033688011112042f   /* 0.125 * log2(e) */
#define THR 8.0f

__global__ __launch_bounds__(256, 4) void attn_flash_mfma(
    const unsigned short* __restrict__ qb,
    const unsigned short* __restrict__ kb,
    const unsigned short* __restrict__ vT,
    unsigned short* __restrict__ yatt,
    int* __restrict__ qctr)
{
    __shared__ unsigned short Ks[2][64 * 64];   // [k][d] swizzled
    __shared__ unsigned short Vs[2][64 * 64];   // [d][k] swizzled

    const int hint = blockIdx.x & 7;
    const int tid  = threadIdx.x;
    const int lane = tid & 63;
    const int wid  = tid >> 6;
    const int l15  = lane & 15;
    const int l4   = lane >> 4;

    bfrag onesf;
    #pragma unroll
    for (int j = 0; j < 8; ++j) onesf[j] = (short)0x3F80;   // bf16 1.0

    for (;;) {
        __syncthreads();                       // prev item's compute done
        if (tid == 0) *(int*)&Ks[0][0] = atomicAdd(&qctr[hint], 1);
        __syncthreads();
        const int it = *(const int*)&Ks[0][0];
        if (it >= 96) break;
        __syncthreads();                       // all read `it` before staging

        const int bh = hint * 6 + (it % 6);
        const int p  = 15 - (it / 6);          // longest first
        const int h = bh % HN, b = bh / HN;
        const int q0 = p * 128;
        const int ktmax = 2 * p + 1;

        const unsigned short* kg = kb + (size_t)b * SEQ * BDIM + h * HDIM;
        const unsigned short* vg = vT + (size_t)bh * HDIM * SEQ;

        // Q fragments (B-operand), two q-halves 64 rows apart
        bfrag qf[2][2];
        {
            const unsigned short* qr0 =
                qb + (size_t)(b * SEQ + q0 + wid * 16 + l15) * BDIM + h * HDIM;
            qf[0][0] = *(const bfrag*)(qr0 + l4 * 8);
            qf[0][1] = *(const bfrag*)(qr0 + 32 + l4 * 8);
            const unsigned short* qr1 = qr0 + (size_t)64 * BDIM;
            qf[1][0] = *(const bfrag*)(qr1 + l4 * 8);
            qf[1][1] = *(const bfrag*)(qr1 + 32 + l4 * 8);
        }

        f32x4 acc0[4] = {}, acc1[4] = {};
        f32x4 accl0 = {}, accl1 = {};
        float m0v = -3.0e38f, m1v = -3.0e38f;

        pfu pf0[2], pf1[2];
        bfrag vr[2][4];
        #pragma unroll
        for (int ks = 0; ks < 2; ++ks) {
            #pragma unroll
            for (int i = 0; i < 4; ++i) { pf0[ks].u[i] = 0u; pf1[ks].u[i] = 0u; }
            #pragma unroll
            for (int ds = 0; ds < 4; ++ds)
                #pragma unroll
                for (int j = 0; j < 8; ++j) vr[ks][ds][j] = 0;
        }

        auto stage = [&](int bufi, int ktile) {
            const int k0 = ktile * 64;
            #pragma unroll
            for (int i = 0; i < 2; ++i) {
                const int row = wid * 16 + i * 8 + (lane >> 3);
                const int ck  = ((lane & 7) ^ (row & 7)) * 8;
                __builtin_amdgcn_global_load_lds(
                    (const __attribute__((address_space(1))) void*)(kg + (size_t)(k0 + row) * BDIM + ck),
                    (__attribute__((address_space(3))) void*)(&Ks[bufi][(wid * 16 + i * 8) * 64]),
                    16, 0, 0);
                __builtin_amdgcn_global_load_lds(
                    (const __attribute__((address_space(1))) void*)(vg + (size_t)row * SEQ + k0 + ck),
                    (__attribute__((address_space(3))) void*)(&Vs[bufi][(wid * 16 + i * 8) * 64]),
                    16, 0, 0);
            }
        };

        // softmax for one q-half: max-reduce, defer-max rescale, exp, P-dance.
        // Row-sum happens later via mfma(pf, ones) in the deferred cluster.
        auto softmax_dance = [&](f32x4* s, float& mm, pfu* pf, f32x4* acc, f32x4& accl) {
            float mx = s[0][0];
            #pragma unroll
            for (int cs = 0; cs < 4; ++cs)
                #pragma unroll
                for (int r = 0; r < 4; ++r) mx = fmaxf(mx, s[cs][r]);
            mx = redmax16(mx);
            mx = redmax32(mx);
            const float mx2 = mx * C2;

            if (!__all(mx2 <= mm + THR)) {
                const float mnew = fmaxf(mm, mx2);
                const float fac  = fexp2(mm - mnew);
                mm = mnew;
                #pragma unroll
                for (int r = 0; r < 4; ++r) {
                    const float fr = __shfl(fac, (lane & 48) | (l4 * 4 + r));
                    #pragma unroll
                    for (int ds = 0; ds < 4; ++ds) acc[ds][r] *= fr;
                    accl[r] *= fr;
                }
            }

            #pragma unroll
            for (int cs = 0; cs < 4; ++cs)
                #pragma unroll
                for (int r = 0; r < 4; ++r)
                    s[cs][r] = fexp2(fmaf(s[cs][r], C2, -mm));

            unsigned pk[4][2];
            #pragma unroll
            for (int cs = 0; cs < 4; ++cs) {
                pk[cs][0] = cvt_pk_bf16(s[cs][0], s[cs][1]);
                pk[cs][1] = cvt_pk_bf16(s[cs][2], s[cs][3]);
            }
            #pragma unroll
            for (int ks = 0; ks < 2; ++ks)
                #pragma unroll
                for (int i = 0; i < 2; ++i) {
#if HAVE_PERMLANE
                    auto r1 = __builtin_amdgcn_permlane32_swap(
                        pk[ks * 2][i], pk[ks * 2 + 1][i], false, false);
                    auto r2 = __builtin_amdgcn_permlane16_swap(r1[0], r1[1], false, false);
                    pf[ks].u[i]     = r2[0];
                    pf[ks].u[2 + i] = r2[1];
#else
                    const unsigned A  = pk[ks * 2][i];
                    const unsigned B  = pk[ks * 2 + 1][i];
                    const unsigned Ax = __shfl_xor(A, 32);
                    const unsigned Bx = __shfl_xor(B, 32);
                    const unsigned P1 = (l4 < 2) ? A : Bx;
                    const unsigned P2 = (l4 < 2) ? Ax : B;
                    const unsigned S1 = __shfl_xor(P1, 16);
                    const unsigned S2 = __shfl_xor(P2, 16);
                    pf[ks].u[i]     = (l4 & 1) ? S2 : P1;
                    pf[ks].u[2 + i] = (l4 & 1) ? P2 : S1;
#endif
                }
        };

        stage(0, 0);
        __syncthreads();

        int buf = 0;
        for (int kt = 0;;) {
            if (kt < ktmax) stage(buf ^ 1, kt + 1);   // async prefetch

            const unsigned short* Kb = Ks[buf];
            const unsigned short* Vb = Vs[buf];

            // ---- MFMA cluster: QK(kt) both halves + deferred PV/rowsum(kt-1)
            f32x4 s0[4] = {}, s1[4] = {};
            __builtin_amdgcn_s_setprio(1);
            #pragma unroll
            for (int ks = 0; ks < 2; ++ks) {
                #pragma unroll
                for (int cs = 0; cs < 4; ++cs) {
                    const int row = cs * 16 + l15;
                    const int ch  = (ks * 4 + l4) ^ (row & 7);
                    const bfrag kf = *(const bfrag*)(Kb + row * 64 + ch * 8);
                    s0[cs] = __builtin_amdgcn_mfma_f32_16x16x32_bf16(kf, qf[0][ks], s0[cs], 0, 0, 0);
                    s1[cs] = __builtin_amdgcn_mfma_f32_16x16x32_bf16(kf, qf[1][ks], s1[cs], 0, 0, 0);
                }
            }
            #pragma unroll
            for (int ks = 0; ks < 2; ++ks) {
                #pragma unroll
                for (int ds = 0; ds < 4; ++ds) {
                    acc0[ds] = __builtin_amdgcn_mfma_f32_16x16x32_bf16(pf0[ks].f, vr[ks][ds], acc0[ds], 0, 0, 0);
                    acc1[ds] = __builtin_amdgcn_mfma_f32_16x16x32_bf16(pf1[ks].f, vr[ks][ds], acc1[ds], 0, 0, 0);
                }
                accl0 = __builtin_amdgcn_mfma_f32_16x16x32_bf16(pf0[ks].f, onesf, accl0, 0, 0, 0);
                accl1 = __builtin_amdgcn_mfma_f32_16x16x32_bf16(pf1[ks].f, onesf, accl1, 0, 0, 0);
            }
            __builtin_amdgcn_s_setprio(0);

            // ---- refill V regs with tile kt ----
            #pragma unroll
            for (int ks = 0; ks < 2; ++ks)
                #pragma unroll
                for (int ds = 0; ds < 4; ++ds) {
                    const int vrow = ds * 16 + l15;
                    const int vch  = (ks * 4 + l4) ^ (vrow & 7);
                    vr[ks][ds] = *(const bfrag*)(Vb + vrow * 64 + vch * 8);
                }

            // ---- causal mask (only the last two K-tiles can clip) ----
            if (kt >= 2 * p) {
                const int qg = q0 + wid * 16 + l15;
                #pragma unroll
                for (int cs = 0; cs < 4; ++cs)
                    #pragma unroll
                    for (int r = 0; r < 4; ++r) {
                        const int kgl = kt * 64 + cs * 16 + l4 * 4 + r;
                        if (kgl > qg)      s0[cs][r] = -3.0e38f;
                        if (kgl > qg + 64) s1[cs][r] = -3.0e38f;
                    }
            }

            softmax_dance(s0, m0v, pf0, acc0, accl0);
            softmax_dance(s1, m1v, pf1, acc1, accl1);

            if (kt == ktmax) break;
            __syncthreads();      // drains own gload_lds + all waves done
            buf ^= 1; ++kt;
        }

        // ---- epilogue: deferred PV + rowsum of final tile ----
        #pragma unroll
        for (int ks = 0; ks < 2; ++ks) {
            #pragma unroll
            for (int ds = 0; ds < 4; ++ds) {
                acc0[ds] = __builtin_amdgcn_mfma_f32_16x16x32_bf16(pf0[ks].f, vr[ks][ds], acc0[ds], 0, 0, 0);
                acc1[ds] = __builtin_amdgcn_mfma_f32_16x16x32_bf16(pf1[ks].f, vr[ks][ds], acc1[ds], 0, 0, 0);
            }
            accl0 = __builtin_amdgcn_mfma_f32_16x16x32_bf16(pf0[ks].f, onesf, accl0, 0, 0, 0);
            accl1 = __builtin_amdgcn_mfma_f32_16x16x32_bf16(pf1[ks].f, onesf, accl1, 0, 0, 0);
        }

        // ---- normalize + store both halves (accl rows match acc rows) ----
        #pragma unroll
        for (int r = 0; r < 4; ++r) {
            const float iv0 = 1.f / accl0[r];
            const float iv1 = 1.f / accl1[r];
            unsigned short* o0 =
                yatt + (size_t)(b * SEQ + q0 + wid * 16 + l4 * 4 + r) * BDIM + h * HDIM;
            unsigned short* o1 = o0 + (size_t)64 * BDIM;
            #pragma unroll
            for (int ds = 0; ds < 4; ++ds) {
                o0[ds * 16 + l15] = f2bf(acc0[ds][r] * iv0);
                o1[ds * 16 + l15] = f2bf(acc1[ds][r] * iv1);
            }
        }
    }
}

// ---------------- launch -----------------------------------------------------
extern "C" void kernel_launch(void* const* d_in, const int* in_sizes, int n_in,
                              void* d_out, int out_size, void* d_ws, size_t ws_size,
                              hipStream_t stream)
{
    const float* x      = (const float*)d_in[0];
    const float* w_qkv  = (const float*)d_in[1];
    const float* b_qkv  = (const float*)d_in[2];
    const float* w_proj = (const float*)d_in[3];
    const float* b_proj = (const float*)d_in[4];
    float* out = (float*)d_out;

    unsigned short* xb   = (unsigned short*)d_ws;                 // [8192][768]
    unsigned short* qb   = xb  + (size_t)MTOT * BDIM;             // [8192][768]
    unsigned short* kbuf = qb  + (size_t)MTOT * BDIM;             // [8192][768]
    unsigned short* vT   = kbuf + (size_t)MTOT * BDIM;            // [4*768][2048]
    unsigned short* yatt = vT  + (size_t)MTOT * BDIM;             // [8192][768]
    unsigned short* wqT  = yatt + (size_t)MTOT * BDIM;            // [2304][768]
    unsigned short* wpT  = wqT + (size_t)3 * BDIM * BDIM;         // [768][768]
    int*            qctr = (int*)(wpT + (size_t)BDIM * BDIM);     // [8]

    // prep
    conv_f32_bf16<<<(MTOT * BDIM / 8 + 255) / 256, 256, 0, stream>>>(
        x, xb, MTOT * BDIM / 8, qctr);
    transpose_f32_bf16<<<dim3(3 * BDIM / 64, BDIM / 64), 256, 0, stream>>>(
        w_qkv, wqT, BDIM, 3 * BDIM);
    transpose_f32_bf16<<<dim3(BDIM / 64, BDIM / 64), 256, 0, stream>>>(
        w_proj, wpT, BDIM, BDIM);

    // qkv GEMM with routed epilogue (Q->qb, K->kb, V->vT transposed)
    gemm_qkv<<<dim3(3 * BDIM / 128, MTOT / 128), 256, 0, stream>>>(
        xb, wqT, b_qkv, qb, kbuf, vT);

    // flash attention (dual q-half items, balanced queues, 4 blocks/CU)
    attn_flash_mfma<<<dim3(1024), 256, 0, stream>>>(qb, kbuf, vT, yatt, qctr);

    // out = yatt @ w_proj + b_proj   (fp32 out, 64x128 tiles)
    gemm_proj<<<dim3(BDIM / 128, MTOT / 64), 256, 0, stream>>>(
        yatt, wpT, b_proj, out);
}

// Round 12
// 141.551 us; speedup vs baseline: 1.6852x; 1.6852x over previous
//
#include <hip/hip_runtime.h>
#include <hip/hip_bf16.h>
#include <cstdint>

#define BDIM 768
#define HN 12
#define HDIM 64
#define SEQ 2048
#define BATCH 4
#define MTOT (BATCH * SEQ)     // 8192

typedef __attribute__((ext_vector_type(8))) short bfrag;   // 8 bf16 (4 VGPR)
typedef __attribute__((ext_vector_type(4))) float f32x4;

union pfu { bfrag f; unsigned u[4]; };

static __device__ __forceinline__ unsigned short f2bf(float f) {
    union { float f; unsigned u; } v; v.f = f;
    unsigned r = v.u + 0x7FFF + ((v.u >> 16) & 1);   // RNE
    return (unsigned short)(r >> 16);
}

static __device__ __forceinline__ float fexp2(float x) {
    float r; asm("v_exp_f32 %0, %1" : "=v"(r) : "v"(x)); return r;
}

static __device__ __forceinline__ unsigned cvt_pk_bf16(float lo, float hi) {
    unsigned r;
    asm("v_cvt_pk_bf16_f32 %0, %1, %2" : "=v"(r) : "v"(lo), "v"(hi));
    return r;
}

// ---- cross-lane helpers: permlane swaps (VALU) with shfl fallback ----------
#if __has_builtin(__builtin_amdgcn_permlane32_swap) && __has_builtin(__builtin_amdgcn_permlane16_swap)
#define HAVE_PERMLANE 1
#else
#define HAVE_PERMLANE 0
#endif

static __device__ __forceinline__ float redmax16(float x) {
#if HAVE_PERMLANE
    union { float f; unsigned u; } a; a.f = x;
    auto r = __builtin_amdgcn_permlane16_swap(a.u, a.u, false, false);
    union { unsigned u; float f; } p, q; p.u = r[0]; q.u = r[1];
    return fmaxf(p.f, q.f);
#else
    return fmaxf(x, __shfl_xor(x, 16));
#endif
}

static __device__ __forceinline__ float redmax32(float x) {
#if HAVE_PERMLANE
    union { float f; unsigned u; } a; a.f = x;
    auto r = __builtin_amdgcn_permlane32_swap(a.u, a.u, false, false);
    union { unsigned u; float f; } p, q; p.u = r[0]; q.u = r[1];
    return fmaxf(p.f, q.f);
#else
    return fmaxf(x, __shfl_xor(x, 32));
#endif
}

// ---------------- prep: fp32 -> bf16 flat convert (+ queue init) -------------
__global__ __launch_bounds__(256) void conv_f32_bf16(
    const float* __restrict__ in, unsigned short* __restrict__ out, int n8,
    int* __restrict__ qctr)
{
    if (blockIdx.x == 0 && threadIdx.x < 8) qctr[threadIdx.x] = 0;
    const int i = blockIdx.x * 256 + threadIdx.x;
    if (i >= n8) return;
    const float4 a = ((const float4*)in)[i * 2];
    const float4 b = ((const float4*)in)[i * 2 + 1];
    bfrag o;
    o[0] = f2bf(a.x); o[1] = f2bf(a.y); o[2] = f2bf(a.z); o[3] = f2bf(a.w);
    o[4] = f2bf(b.x); o[5] = f2bf(b.y); o[6] = f2bf(b.z); o[7] = f2bf(b.w);
    ((bfrag*)out)[i] = o;
}

// ---------------- prep: [R][C] fp32 -> [C][R] bf16 transpose ----------------
__global__ __launch_bounds__(256) void transpose_f32_bf16(
    const float* __restrict__ in, unsigned short* __restrict__ out, int R, int C)
{
    __shared__ unsigned short t[64][72];
    const int tid = threadIdx.x;
    const int c0 = blockIdx.x * 64, r0 = blockIdx.y * 64;
    #pragma unroll
    for (int i = 0; i < 4; ++i) {
        const int r = (tid >> 4) + i * 16;
        const int c = (tid & 15) * 4;
        const float4 v = *(const float4*)&in[(size_t)(r0 + r) * C + c0 + c];
        t[c + 0][r] = f2bf(v.x);
        t[c + 1][r] = f2bf(v.y);
        t[c + 2][r] = f2bf(v.z);
        t[c + 3][r] = f2bf(v.w);
    }
    __syncthreads();
    #pragma unroll
    for (int i = 0; i < 2; ++i) {
        const int c = (tid >> 3) + i * 32;
        const int r = (tid & 7) * 8;
        *(bfrag*)&out[(size_t)(c0 + c) * R + r0 + r] = *(const bfrag*)&t[c][r];
    }
}

// ---------------- GEMM1: qkv = x @ wqT^T + b, routed to qb/kb/vT ------------
__global__ __launch_bounds__(256) void gemm_qkv(
    const unsigned short* __restrict__ A,
    const unsigned short* __restrict__ Bt,
    const float* __restrict__ bias,
    unsigned short* __restrict__ qb,
    unsigned short* __restrict__ kb,
    unsigned short* __restrict__ vTt)
{
    __shared__ unsigned short As[128 * 64];
    __shared__ unsigned short Bs[128 * 64];

    const int tid  = threadIdx.x;
    const int lane = tid & 63;
    const int wid  = tid >> 6;
    const int l15  = lane & 15;
    const int l4   = lane >> 4;
    const int m0 = blockIdx.y * 128;
    const int n0 = blockIdx.x * 128;
    const int wm = (wid >> 1) * 64;
    const int wn = (wid & 1) * 64;

    f32x4 acc[4][4] = {};

    for (int k0 = 0; k0 < BDIM; k0 += 64) {
        __syncthreads();
        #pragma unroll
        for (int i = 0; i < 4; ++i) {
            const int row = wid * 32 + i * 8 + (lane >> 3);
            const int ck  = (((lane & 7) ^ (row & 7)) * 8);
            __builtin_amdgcn_global_load_lds(
                (const __attribute__((address_space(1))) void*)(A + (size_t)(m0 + row) * BDIM + k0 + ck),
                (__attribute__((address_space(3))) void*)(As + (wid * 4 + i) * 512),
                16, 0, 0);
            __builtin_amdgcn_global_load_lds(
                (const __attribute__((address_space(1))) void*)(Bt + (size_t)(n0 + row) * BDIM + k0 + ck),
                (__attribute__((address_space(3))) void*)(Bs + (wid * 4 + i) * 512),
                16, 0, 0);
        }
        __syncthreads();

        #pragma unroll
        for (int ks = 0; ks < 2; ++ks) {
            bfrag af[4], bfv[4];
            #pragma unroll
            for (int mi = 0; mi < 4; ++mi) {
                const int row = wm + mi * 16 + l15;
                const int ch  = (ks * 4 + l4) ^ (row & 7);
                af[mi] = *(const bfrag*)(As + row * 64 + ch * 8);
            }
            #pragma unroll
            for (int ni = 0; ni < 4; ++ni) {
                const int row = wn + ni * 16 + l15;
                const int ch  = (ks * 4 + l4) ^ (row & 7);
                bfv[ni] = *(const bfrag*)(Bs + row * 64 + ch * 8);
            }
            #pragma unroll
            for (int mi = 0; mi < 4; ++mi)
                #pragma unroll
                for (int ni = 0; ni < 4; ++ni)
                    acc[mi][ni] = __builtin_amdgcn_mfma_f32_16x16x32_bf16(
                        af[mi], bfv[ni], acc[mi][ni], 0, 0, 0);
        }
    }

    const int nb = n0 + wn;
    if (nb < 1536) {
        unsigned short* dst = (nb < 768) ? qb : kb;
        const int coff = (nb < 768) ? 0 : 768;
        #pragma unroll
        for (int mi = 0; mi < 4; ++mi)
            #pragma unroll
            for (int ni = 0; ni < 4; ++ni) {
                const int n = nb + ni * 16 + l15;
                const float bv = bias[n];
                #pragma unroll
                for (int r = 0; r < 4; ++r) {
                    const int m = m0 + wm + mi * 16 + l4 * 4 + r;
                    dst[(size_t)m * BDIM + (n - coff)] = f2bf(acc[mi][ni][r] + bv);
                }
            }
    } else {
        // V block: write transposed into vT[(b*768 + n-1536)][s]
        #pragma unroll
        for (int mi = 0; mi < 4; ++mi)
            #pragma unroll
            for (int ni = 0; ni < 4; ++ni) {
                const int n = nb + ni * 16 + l15;
                const float bv = bias[n];
                const size_t vrow = (size_t)(m0 >> 11) * 768 + (n - 1536);
                const int mbase = m0 + wm + mi * 16 + l4 * 4;
                const int scol = mbase & (SEQ - 1);
                uint2 u2;
                u2.x = (unsigned)f2bf(acc[mi][ni][0] + bv)
                     | ((unsigned)f2bf(acc[mi][ni][1] + bv) << 16);
                u2.y = (unsigned)f2bf(acc[mi][ni][2] + bv)
                     | ((unsigned)f2bf(acc[mi][ni][3] + bv) << 16);
                *(uint2*)(vTt + vrow * SEQ + scol) = u2;
            }
    }
}

// ---------------- GEMM2: out = yatt @ wpT^T + b (fp32 out), 64x128 tiles ----
__global__ __launch_bounds__(256) void gemm_proj(
    const unsigned short* __restrict__ A,   // [8192][768] bf16
    const unsigned short* __restrict__ Bt,  // [768][768] bf16
    const float* __restrict__ bias,
    float* __restrict__ C)
{
    __shared__ unsigned short As[64 * 64];    // 64 M-rows x 64 k
    __shared__ unsigned short Bs[128 * 64];   // 128 N-rows x 64 k

    const int tid  = threadIdx.x;
    const int lane = tid & 63;
    const int wid  = tid >> 6;
    const int l15  = lane & 15;
    const int l4   = lane >> 4;
    const int m0 = blockIdx.y * 64;
    const int n0 = blockIdx.x * 128;
    const int wm = (wid >> 1) * 32;    // 2 m-sub of 32 rows
    const int wn = (wid & 1) * 64;

    f32x4 acc[2][4] = {};

    for (int k0 = 0; k0 < BDIM; k0 += 64) {
        __syncthreads();
        #pragma unroll
        for (int i = 0; i < 2; ++i) {   // A: 64 rows, 2 instr/wave
            const int row = wid * 16 + i * 8 + (lane >> 3);
            const int ck  = (((lane & 7) ^ (row & 7)) * 8);
            __builtin_amdgcn_global_load_lds(
                (const __attribute__((address_space(1))) void*)(A + (size_t)(m0 + row) * BDIM + k0 + ck),
                (__attribute__((address_space(3))) void*)(As + (wid * 16 + i * 8) * 64),
                16, 0, 0);
        }
        #pragma unroll
        for (int i = 0; i < 4; ++i) {   // B: 128 rows, 4 instr/wave
            const int row = wid * 32 + i * 8 + (lane >> 3);
            const int ck  = (((lane & 7) ^ (row & 7)) * 8);
            __builtin_amdgcn_global_load_lds(
                (const __attribute__((address_space(1))) void*)(Bt + (size_t)(n0 + row) * BDIM + k0 + ck),
                (__attribute__((address_space(3))) void*)(Bs + (wid * 32 + i * 8) * 64),
                16, 0, 0);
        }
        __syncthreads();

        #pragma unroll
        for (int ks = 0; ks < 2; ++ks) {
            bfrag af[2], bfv[4];
            #pragma unroll
            for (int mi = 0; mi < 2; ++mi) {
                const int row = wm + mi * 16 + l15;
                const int ch  = (ks * 4 + l4) ^ (row & 7);
                af[mi] = *(const bfrag*)(As + row * 64 + ch * 8);
            }
            #pragma unroll
            for (int ni = 0; ni < 4; ++ni) {
                const int row = wn + ni * 16 + l15;
                const int ch  = (ks * 4 + l4) ^ (row & 7);
                bfv[ni] = *(const bfrag*)(Bs + row * 64 + ch * 8);
            }
            #pragma unroll
            for (int mi = 0; mi < 2; ++mi)
                #pragma unroll
                for (int ni = 0; ni < 4; ++ni)
                    acc[mi][ni] = __builtin_amdgcn_mfma_f32_16x16x32_bf16(
                        af[mi], bfv[ni], acc[mi][ni], 0, 0, 0);
        }
    }

    #pragma unroll
    for (int mi = 0; mi < 2; ++mi)
        #pragma unroll
        for (int ni = 0; ni < 4; ++ni) {
            const int n = n0 + wn + ni * 16 + l15;
            const float bv = bias[n];
            #pragma unroll
            for (int r = 0; r < 4; ++r) {
                const int m = m0 + wm + mi * 16 + l4 * 4 + r;
                C[(size_t)m * BDIM + n] = acc[mi][ni][r] + bv;
            }
        }
}

// ---------------- MFMA flash attention: dual q-half, MFMA row-sum -----------
// Item = (bh, p): q-rows [p*128, p*128+128), K-tiles 0..2p+1. 768 items,
// longest-first, 8 queues x 96; grid 1024 (4 blocks/CU resident naturally:
// VGPR~100 -> 4x4 waves @ 400<=512 regs/SIMD, LDS 4x32<=160 KB).
#define C2 0.18033688011112042f   /* 0.125 * log2(e) */
#define THR 8.0f

__global__ __launch_bounds__(256, 2) void attn_flash_mfma(
    const unsigned short* __restrict__ qb,
    const unsigned short* __restrict__ kb,
    const unsigned short* __restrict__ vT,
    unsigned short* __restrict__ yatt,
    int* __restrict__ qctr)
{
    __shared__ unsigned short Ks[2][64 * 64];   // [k][d] swizzled
    __shared__ unsigned short Vs[2][64 * 64];   // [d][k] swizzled

    const int hint = blockIdx.x & 7;
    const int tid  = threadIdx.x;
    const int lane = tid & 63;
    const int wid  = tid >> 6;
    const int l15  = lane & 15;
    const int l4   = lane >> 4;

    bfrag onesf;
    #pragma unroll
    for (int j = 0; j < 8; ++j) onesf[j] = (short)0x3F80;   // bf16 1.0

    for (;;) {
        __syncthreads();                       // prev item's compute done
        if (tid == 0) *(int*)&Ks[0][0] = atomicAdd(&qctr[hint], 1);
        __syncthreads();
        const int it = *(const int*)&Ks[0][0];
        if (it >= 96) break;
        __syncthreads();                       // all read `it` before staging

        const int bh = hint * 6 + (it % 6);
        const int p  = 15 - (it / 6);          // longest first
        const int h = bh % HN, b = bh / HN;
        const int q0 = p * 128;
        const int ktmax = 2 * p + 1;

        const unsigned short* kg = kb + (size_t)b * SEQ * BDIM + h * HDIM;
        const unsigned short* vg = vT + (size_t)bh * HDIM * SEQ;

        // Q fragments (B-operand), two q-halves 64 rows apart
        bfrag qf[2][2];
        {
            const unsigned short* qr0 =
                qb + (size_t)(b * SEQ + q0 + wid * 16 + l15) * BDIM + h * HDIM;
            qf[0][0] = *(const bfrag*)(qr0 + l4 * 8);
            qf[0][1] = *(const bfrag*)(qr0 + 32 + l4 * 8);
            const unsigned short* qr1 = qr0 + (size_t)64 * BDIM;
            qf[1][0] = *(const bfrag*)(qr1 + l4 * 8);
            qf[1][1] = *(const bfrag*)(qr1 + 32 + l4 * 8);
        }

        f32x4 acc0[4] = {}, acc1[4] = {};
        f32x4 accl0 = {}, accl1 = {};
        float m0v = -3.0e38f, m1v = -3.0e38f;

        pfu pf0[2], pf1[2];
        bfrag vr[2][4];
        #pragma unroll
        for (int ks = 0; ks < 2; ++ks) {
            #pragma unroll
            for (int i = 0; i < 4; ++i) { pf0[ks].u[i] = 0u; pf1[ks].u[i] = 0u; }
            #pragma unroll
            for (int ds = 0; ds < 4; ++ds)
                #pragma unroll
                for (int j = 0; j < 8; ++j) vr[ks][ds][j] = 0;
        }

        auto stage = [&](int bufi, int ktile) {
            const int k0 = ktile * 64;
            #pragma unroll
            for (int i = 0; i < 2; ++i) {
                const int row = wid * 16 + i * 8 + (lane >> 3);
                const int ck  = ((lane & 7) ^ (row & 7)) * 8;
                __builtin_amdgcn_global_load_lds(
                    (const __attribute__((address_space(1))) void*)(kg + (size_t)(k0 + row) * BDIM + ck),
                    (__attribute__((address_space(3))) void*)(&Ks[bufi][(wid * 16 + i * 8) * 64]),
                    16, 0, 0);
                __builtin_amdgcn_global_load_lds(
                    (const __attribute__((address_space(1))) void*)(vg + (size_t)row * SEQ + k0 + ck),
                    (__attribute__((address_space(3))) void*)(&Vs[bufi][(wid * 16 + i * 8) * 64]),
                    16, 0, 0);
            }
        };

        // softmax for one q-half: max-reduce, defer-max rescale, exp, P-dance.
        // Row-sum happens later via mfma(pf, ones) in the deferred cluster.
        auto softmax_dance = [&](f32x4* s, float& mm, pfu* pf, f32x4* acc, f32x4& accl) {
            float mx = s[0][0];
            #pragma unroll
            for (int cs = 0; cs < 4; ++cs)
                #pragma unroll
                for (int r = 0; r < 4; ++r) mx = fmaxf(mx, s[cs][r]);
            mx = redmax16(mx);
            mx = redmax32(mx);
            const float mx2 = mx * C2;

            if (!__all(mx2 <= mm + THR)) {
                const float mnew = fmaxf(mm, mx2);
                const float fac  = fexp2(mm - mnew);
                mm = mnew;
                #pragma unroll
                for (int r = 0; r < 4; ++r) {
                    const float fr = __shfl(fac, (lane & 48) | (l4 * 4 + r));
                    #pragma unroll
                    for (int ds = 0; ds < 4; ++ds) acc[ds][r] *= fr;
                    accl[r] *= fr;
                }
            }

            #pragma unroll
            for (int cs = 0; cs < 4; ++cs)
                #pragma unroll
                for (int r = 0; r < 4; ++r)
                    s[cs][r] = fexp2(fmaf(s[cs][r], C2, -mm));

            unsigned pk[4][2];
            #pragma unroll
            for (int cs = 0; cs < 4; ++cs) {
                pk[cs][0] = cvt_pk_bf16(s[cs][0], s[cs][1]);
                pk[cs][1] = cvt_pk_bf16(s[cs][2], s[cs][3]);
            }
            #pragma unroll
            for (int ks = 0; ks < 2; ++ks)
                #pragma unroll
                for (int i = 0; i < 2; ++i) {
#if HAVE_PERMLANE
                    auto r1 = __builtin_amdgcn_permlane32_swap(
                        pk[ks * 2][i], pk[ks * 2 + 1][i], false, false);
                    auto r2 = __builtin_amdgcn_permlane16_swap(r1[0], r1[1], false, false);
                    pf[ks].u[i]     = r2[0];
                    pf[ks].u[2 + i] = r2[1];
#else
                    const unsigned A  = pk[ks * 2][i];
                    const unsigned B  = pk[ks * 2 + 1][i];
                    const unsigned Ax = __shfl_xor(A, 32);
                    const unsigned Bx = __shfl_xor(B, 32);
                    const unsigned P1 = (l4 < 2) ? A : Bx;
                    const unsigned P2 = (l4 < 2) ? Ax : B;
                    const unsigned S1 = __shfl_xor(P1, 16);
                    const unsigned S2 = __shfl_xor(P2, 16);
                    pf[ks].u[i]     = (l4 & 1) ? S2 : P1;
                    pf[ks].u[2 + i] = (l4 & 1) ? P2 : S1;
#endif
                }
        };

        stage(0, 0);
        __syncthreads();

        int buf = 0;
        for (int kt = 0;;) {
            if (kt < ktmax) stage(buf ^ 1, kt + 1);   // async prefetch

            const unsigned short* Kb = Ks[buf];
            const unsigned short* Vb = Vs[buf];

            // ---- MFMA cluster: QK(kt) both halves + deferred PV/rowsum(kt-1)
            f32x4 s0[4] = {}, s1[4] = {};
            __builtin_amdgcn_s_setprio(1);
            #pragma unroll
            for (int ks = 0; ks < 2; ++ks) {
                #pragma unroll
                for (int cs = 0; cs < 4; ++cs) {
                    const int row = cs * 16 + l15;
                    const int ch  = (ks * 4 + l4) ^ (row & 7);
                    const bfrag kf = *(const bfrag*)(Kb + row * 64 + ch * 8);
                    s0[cs] = __builtin_amdgcn_mfma_f32_16x16x32_bf16(kf, qf[0][ks], s0[cs], 0, 0, 0);
                    s1[cs] = __builtin_amdgcn_mfma_f32_16x16x32_bf16(kf, qf[1][ks], s1[cs], 0, 0, 0);
                }
            }
            #pragma unroll
            for (int ks = 0; ks < 2; ++ks) {
                #pragma unroll
                for (int ds = 0; ds < 4; ++ds) {
                    acc0[ds] = __builtin_amdgcn_mfma_f32_16x16x32_bf16(pf0[ks].f, vr[ks][ds], acc0[ds], 0, 0, 0);
                    acc1[ds] = __builtin_amdgcn_mfma_f32_16x16x32_bf16(pf1[ks].f, vr[ks][ds], acc1[ds], 0, 0, 0);
                }
                accl0 = __builtin_amdgcn_mfma_f32_16x16x32_bf16(pf0[ks].f, onesf, accl0, 0, 0, 0);
                accl1 = __builtin_amdgcn_mfma_f32_16x16x32_bf16(pf1[ks].f, onesf, accl1, 0, 0, 0);
            }
            __builtin_amdgcn_s_setprio(0);

            // ---- refill V regs with tile kt ----
            #pragma unroll
            for (int ks = 0; ks < 2; ++ks)
                #pragma unroll
                for (int ds = 0; ds < 4; ++ds) {
                    const int vrow = ds * 16 + l15;
                    const int vch  = (ks * 4 + l4) ^ (vrow & 7);
                    vr[ks][ds] = *(const bfrag*)(Vb + vrow * 64 + vch * 8);
                }

            // ---- causal mask (only the last two K-tiles can clip) ----
            if (kt >= 2 * p) {
                const int qg = q0 + wid * 16 + l15;
                #pragma unroll
                for (int cs = 0; cs < 4; ++cs)
                    #pragma unroll
                    for (int r = 0; r < 4; ++r) {
                        const int kgl = kt * 64 + cs * 16 + l4 * 4 + r;
                        if (kgl > qg)      s0[cs][r] = -3.0e38f;
                        if (kgl > qg + 64) s1[cs][r] = -3.0e38f;
                    }
            }

            softmax_dance(s0, m0v, pf0, acc0, accl0);
            softmax_dance(s1, m1v, pf1, acc1, accl1);

            if (kt == ktmax) break;
            __syncthreads();      // drains own gload_lds + all waves done
            buf ^= 1; ++kt;
        }

        // ---- epilogue: deferred PV + rowsum of final tile ----
        #pragma unroll
        for (int ks = 0; ks < 2; ++ks) {
            #pragma unroll
            for (int ds = 0; ds < 4; ++ds) {
                acc0[ds] = __builtin_amdgcn_mfma_f32_16x16x32_bf16(pf0[ks].f, vr[ks][ds], acc0[ds], 0, 0, 0);
                acc1[ds] = __builtin_amdgcn_mfma_f32_16x16x32_bf16(pf1[ks].f, vr[ks][ds], acc1[ds], 0, 0, 0);
            }
            accl0 = __builtin_amdgcn_mfma_f32_16x16x32_bf16(pf0[ks].f, onesf, accl0, 0, 0, 0);
            accl1 = __builtin_amdgcn_mfma_f32_16x16x32_bf16(pf1[ks].f, onesf, accl1, 0, 0, 0);
        }

        // ---- normalize + store both halves (accl rows match acc rows) ----
        #pragma unroll
        for (int r = 0; r < 4; ++r) {
            const float iv0 = 1.f / accl0[r];
            const float iv1 = 1.f / accl1[r];
            unsigned short* o0 =
                yatt + (size_t)(b * SEQ + q0 + wid * 16 + l4 * 4 + r) * BDIM + h * HDIM;
            unsigned short* o1 = o0 + (size_t)64 * BDIM;
            #pragma unroll
            for (int ds = 0; ds < 4; ++ds) {
                o0[ds * 16 + l15] = f2bf(acc0[ds][r] * iv0);
                o1[ds * 16 + l15] = f2bf(acc1[ds][r] * iv1);
            }
        }
    }
}

// ---------------- launch -----------------------------------------------------
extern "C" void kernel_launch(void* const* d_in, const int* in_sizes, int n_in,
                              void* d_out, int out_size, void* d_ws, size_t ws_size,
                              hipStream_t stream)
{
    const float* x      = (const float*)d_in[0];
    const float* w_qkv  = (const float*)d_in[1];
    const float* b_qkv  = (const float*)d_in[2];
    const float* w_proj = (const float*)d_in[3];
    const float* b_proj = (const float*)d_in[4];
    float* out = (float*)d_out;

    unsigned short* xb   = (unsigned short*)d_ws;                 // [8192][768]
    unsigned short* qb   = xb  + (size_t)MTOT * BDIM;             // [8192][768]
    unsigned short* kbuf = qb  + (size_t)MTOT * BDIM;             // [8192][768]
    unsigned short* vT   = kbuf + (size_t)MTOT * BDIM;            // [4*768][2048]
    unsigned short* yatt = vT  + (size_t)MTOT * BDIM;             // [8192][768]
    unsigned short* wqT  = yatt + (size_t)MTOT * BDIM;            // [2304][768]
    unsigned short* wpT  = wqT + (size_t)3 * BDIM * BDIM;         // [768][768]
    int*            qctr = (int*)(wpT + (size_t)BDIM * BDIM);     // [8]

    // prep
    conv_f32_bf16<<<(MTOT * BDIM / 8 + 255) / 256, 256, 0, stream>>>(
        x, xb, MTOT * BDIM / 8, qctr);
    transpose_f32_bf16<<<dim3(3 * BDIM / 64, BDIM / 64), 256, 0, stream>>>(
        w_qkv, wqT, BDIM, 3 * BDIM);
    transpose_f32_bf16<<<dim3(BDIM / 64, BDIM / 64), 256, 0, stream>>>(
        w_proj, wpT, BDIM, BDIM);

    // qkv GEMM with routed epilogue (Q->qb, K->kb, V->vT transposed)
    gemm_qkv<<<dim3(3 * BDIM / 128, MTOT / 128), 256, 0, stream>>>(
        xb, wqT, b_qkv, qb, kbuf, vT);

    // flash attention (dual q-half items, balanced queues, grid 1024)
    attn_flash_mfma<<<dim3(1024), 256, 0, stream>>>(qb, kbuf, vT, yatt, qctr);

    // out = yatt @ w_proj + b_proj   (fp32 out, 64x128 tiles)
    gemm_proj<<<dim3(BDIM / 128, MTOT / 64), 256, 0, stream>>>(
        yatt, wpT, b_proj, out);
}

// Round 13
// 140.379 us; speedup vs baseline: 1.6993x; 1.0083x over previous
//
#include <hip/hip_runtime.h>
#include <hip/hip_bf16.h>
#include <cstdint>

#define BDIM 768
#define HN 12
#define HDIM 64
#define SEQ 2048
#define BATCH 4
#define MTOT (BATCH * SEQ)     // 8192

typedef __attribute__((ext_vector_type(8))) short bfrag;   // 8 bf16 (4 VGPR)
typedef __attribute__((ext_vector_type(4))) float f32x4;

union pfu { bfrag f; unsigned u[4]; };

static __device__ __forceinline__ unsigned short f2bf(float f) {
    union { float f; unsigned u; } v; v.f = f;
    unsigned r = v.u + 0x7FFF + ((v.u >> 16) & 1);   // RNE
    return (unsigned short)(r >> 16);
}

static __device__ __forceinline__ float fexp2(float x) {
    float r; asm("v_exp_f32 %0, %1" : "=v"(r) : "v"(x)); return r;
}

static __device__ __forceinline__ unsigned cvt_pk_bf16(float lo, float hi) {
    unsigned r;
    asm("v_cvt_pk_bf16_f32 %0, %1, %2" : "=v"(r) : "v"(lo), "v"(hi));
    return r;
}

// ---- cross-lane helpers: permlane swaps (VALU) with shfl fallback ----------
#if __has_builtin(__builtin_amdgcn_permlane32_swap) && __has_builtin(__builtin_amdgcn_permlane16_swap)
#define HAVE_PERMLANE 1
#else
#define HAVE_PERMLANE 0
#endif

static __device__ __forceinline__ float redmax16(float x) {
#if HAVE_PERMLANE
    union { float f; unsigned u; } a; a.f = x;
    auto r = __builtin_amdgcn_permlane16_swap(a.u, a.u, false, false);
    union { unsigned u; float f; } p, q; p.u = r[0]; q.u = r[1];
    return fmaxf(p.f, q.f);
#else
    return fmaxf(x, __shfl_xor(x, 16));
#endif
}

static __device__ __forceinline__ float redmax32(float x) {
#if HAVE_PERMLANE
    union { float f; unsigned u; } a; a.f = x;
    auto r = __builtin_amdgcn_permlane32_swap(a.u, a.u, false, false);
    union { unsigned u; float f; } p, q; p.u = r[0]; q.u = r[1];
    return fmaxf(p.f, q.f);
#else
    return fmaxf(x, __shfl_xor(x, 32));
#endif
}

// ---------------- prep: fp32 -> bf16 flat convert ----------------------------
__global__ __launch_bounds__(256) void conv_f32_bf16(
    const float* __restrict__ in, unsigned short* __restrict__ out, int n8)
{
    const int i = blockIdx.x * 256 + threadIdx.x;
    if (i >= n8) return;
    const float4 a = ((const float4*)in)[i * 2];
    const float4 b = ((const float4*)in)[i * 2 + 1];
    bfrag o;
    o[0] = f2bf(a.x); o[1] = f2bf(a.y); o[2] = f2bf(a.z); o[3] = f2bf(a.w);
    o[4] = f2bf(b.x); o[5] = f2bf(b.y); o[6] = f2bf(b.z); o[7] = f2bf(b.w);
    ((bfrag*)out)[i] = o;
}

// ---------------- prep: [R][C] fp32 -> [C][R] bf16 transpose ----------------
__global__ __launch_bounds__(256) void transpose_f32_bf16(
    const float* __restrict__ in, unsigned short* __restrict__ out, int R, int C)
{
    __shared__ unsigned short t[64][72];
    const int tid = threadIdx.x;
    const int c0 = blockIdx.x * 64, r0 = blockIdx.y * 64;
    #pragma unroll
    for (int i = 0; i < 4; ++i) {
        const int r = (tid >> 4) + i * 16;
        const int c = (tid & 15) * 4;
        const float4 v = *(const float4*)&in[(size_t)(r0 + r) * C + c0 + c];
        t[c + 0][r] = f2bf(v.x);
        t[c + 1][r] = f2bf(v.y);
        t[c + 2][r] = f2bf(v.z);
        t[c + 3][r] = f2bf(v.w);
    }
    __syncthreads();
    #pragma unroll
    for (int i = 0; i < 2; ++i) {
        const int c = (tid >> 3) + i * 32;
        const int r = (tid & 7) * 8;
        *(bfrag*)&out[(size_t)(c0 + c) * R + r0 + r] = *(const bfrag*)&t[c][r];
    }
}

// ---------------- GEMM1: qkv = x @ wqT^T + b, routed to qb/kb/vT ------------
__global__ __launch_bounds__(256) void gemm_qkv(
    const unsigned short* __restrict__ A,
    const unsigned short* __restrict__ Bt,
    const float* __restrict__ bias,
    unsigned short* __restrict__ qb,
    unsigned short* __restrict__ kb,
    unsigned short* __restrict__ vTt)
{
    __shared__ unsigned short As[128 * 64];
    __shared__ unsigned short Bs[128 * 64];

    const int tid  = threadIdx.x;
    const int lane = tid & 63;
    const int wid  = tid >> 6;
    const int l15  = lane & 15;
    const int l4   = lane >> 4;
    const int m0 = blockIdx.y * 128;
    const int n0 = blockIdx.x * 128;
    const int wm = (wid >> 1) * 64;
    const int wn = (wid & 1) * 64;

    f32x4 acc[4][4] = {};

    for (int k0 = 0; k0 < BDIM; k0 += 64) {
        __syncthreads();
        #pragma unroll
        for (int i = 0; i < 4; ++i) {
            const int row = wid * 32 + i * 8 + (lane >> 3);
            const int ck  = (((lane & 7) ^ (row & 7)) * 8);
            __builtin_amdgcn_global_load_lds(
                (const __attribute__((address_space(1))) void*)(A + (size_t)(m0 + row) * BDIM + k0 + ck),
                (__attribute__((address_space(3))) void*)(As + (wid * 4 + i) * 512),
                16, 0, 0);
            __builtin_amdgcn_global_load_lds(
                (const __attribute__((address_space(1))) void*)(Bt + (size_t)(n0 + row) * BDIM + k0 + ck),
                (__attribute__((address_space(3))) void*)(Bs + (wid * 4 + i) * 512),
                16, 0, 0);
        }
        __syncthreads();

        #pragma unroll
        for (int ks = 0; ks < 2; ++ks) {
            bfrag af[4], bfv[4];
            #pragma unroll
            for (int mi = 0; mi < 4; ++mi) {
                const int row = wm + mi * 16 + l15;
                const int ch  = (ks * 4 + l4) ^ (row & 7);
                af[mi] = *(const bfrag*)(As + row * 64 + ch * 8);
            }
            #pragma unroll
            for (int ni = 0; ni < 4; ++ni) {
                const int row = wn + ni * 16 + l15;
                const int ch  = (ks * 4 + l4) ^ (row & 7);
                bfv[ni] = *(const bfrag*)(Bs + row * 64 + ch * 8);
            }
            #pragma unroll
            for (int mi = 0; mi < 4; ++mi)
                #pragma unroll
                for (int ni = 0; ni < 4; ++ni)
                    acc[mi][ni] = __builtin_amdgcn_mfma_f32_16x16x32_bf16(
                        af[mi], bfv[ni], acc[mi][ni], 0, 0, 0);
        }
    }

    const int nb = n0 + wn;
    if (nb < 1536) {
        unsigned short* dst = (nb < 768) ? qb : kb;
        const int coff = (nb < 768) ? 0 : 768;
        #pragma unroll
        for (int mi = 0; mi < 4; ++mi)
            #pragma unroll
            for (int ni = 0; ni < 4; ++ni) {
                const int n = nb + ni * 16 + l15;
                const float bv = bias[n];
                #pragma unroll
                for (int r = 0; r < 4; ++r) {
                    const int m = m0 + wm + mi * 16 + l4 * 4 + r;
                    dst[(size_t)m * BDIM + (n - coff)] = f2bf(acc[mi][ni][r] + bv);
                }
            }
    } else {
        // V block: write transposed into vT[(b*768 + n-1536)][s]
        #pragma unroll
        for (int mi = 0; mi < 4; ++mi)
            #pragma unroll
            for (int ni = 0; ni < 4; ++ni) {
                const int n = nb + ni * 16 + l15;
                const float bv = bias[n];
                const size_t vrow = (size_t)(m0 >> 11) * 768 + (n - 1536);
                const int mbase = m0 + wm + mi * 16 + l4 * 4;
                const int scol = mbase & (SEQ - 1);
                uint2 u2;
                u2.x = (unsigned)f2bf(acc[mi][ni][0] + bv)
                     | ((unsigned)f2bf(acc[mi][ni][1] + bv) << 16);
                u2.y = (unsigned)f2bf(acc[mi][ni][2] + bv)
                     | ((unsigned)f2bf(acc[mi][ni][3] + bv) << 16);
                *(uint2*)(vTt + vrow * SEQ + scol) = u2;
            }
    }
}

// ---------------- GEMM2: out = yatt @ wpT^T + b (fp32 out), 64x128 tiles ----
__global__ __launch_bounds__(256) void gemm_proj(
    const unsigned short* __restrict__ A,   // [8192][768] bf16
    const unsigned short* __restrict__ Bt,  // [768][768] bf16
    const float* __restrict__ bias,
    float* __restrict__ C)
{
    __shared__ unsigned short As[64 * 64];    // 64 M-rows x 64 k
    __shared__ unsigned short Bs[128 * 64];   // 128 N-rows x 64 k

    const int tid  = threadIdx.x;
    const int lane = tid & 63;
    const int wid  = tid >> 6;
    const int l15  = lane & 15;
    const int l4   = lane >> 4;
    const int m0 = blockIdx.y * 64;
    const int n0 = blockIdx.x * 128;
    const int wm = (wid >> 1) * 32;    // 2 m-sub of 32 rows
    const int wn = (wid & 1) * 64;

    f32x4 acc[2][4] = {};

    for (int k0 = 0; k0 < BDIM; k0 += 64) {
        __syncthreads();
        #pragma unroll
        for (int i = 0; i < 2; ++i) {   // A: 64 rows, 2 instr/wave
            const int row = wid * 16 + i * 8 + (lane >> 3);
            const int ck  = (((lane & 7) ^ (row & 7)) * 8);
            __builtin_amdgcn_global_load_lds(
                (const __attribute__((address_space(1))) void*)(A + (size_t)(m0 + row) * BDIM + k0 + ck),
                (__attribute__((address_space(3))) void*)(As + (wid * 16 + i * 8) * 64),
                16, 0, 0);
        }
        #pragma unroll
        for (int i = 0; i < 4; ++i) {   // B: 128 rows, 4 instr/wave
            const int row = wid * 32 + i * 8 + (lane >> 3);
            const int ck  = (((lane & 7) ^ (row & 7)) * 8);
            __builtin_amdgcn_global_load_lds(
                (const __attribute__((address_space(1))) void*)(Bt + (size_t)(n0 + row) * BDIM + k0 + ck),
                (__attribute__((address_space(3))) void*)(Bs + (wid * 32 + i * 8) * 64),
                16, 0, 0);
        }
        __syncthreads();

        #pragma unroll
        for (int ks = 0; ks < 2; ++ks) {
            bfrag af[2], bfv[4];
            #pragma unroll
            for (int mi = 0; mi < 2; ++mi) {
                const int row = wm + mi * 16 + l15;
                const int ch  = (ks * 4 + l4) ^ (row & 7);
                af[mi] = *(const bfrag*)(As + row * 64 + ch * 8);
            }
            #pragma unroll
            for (int ni = 0; ni < 4; ++ni) {
                const int row = wn + ni * 16 + l15;
                const int ch  = (ks * 4 + l4) ^ (row & 7);
                bfv[ni] = *(const bfrag*)(Bs + row * 64 + ch * 8);
            }
            #pragma unroll
            for (int mi = 0; mi < 2; ++mi)
                #pragma unroll
                for (int ni = 0; ni < 4; ++ni)
                    acc[mi][ni] = __builtin_amdgcn_mfma_f32_16x16x32_bf16(
                        af[mi], bfv[ni], acc[mi][ni], 0, 0, 0);
        }
    }

    #pragma unroll
    for (int mi = 0; mi < 2; ++mi)
        #pragma unroll
        for (int ni = 0; ni < 4; ++ni) {
            const int n = n0 + wn + ni * 16 + l15;
            const float bv = bias[n];
            #pragma unroll
            for (int r = 0; r < 4; ++r) {
                const int m = m0 + wm + mi * 16 + l4 * 4 + r;
                C[(size_t)m * BDIM + n] = acc[mi][ni][r] + bv;
            }
        }
}

// ---------------- MFMA flash attention: dual q-half, causal-paired items ----
// Static item = (bh, j): segment A = q-pair j (K-steps 2j+2), segment B =
// q-pair 15-j (K-steps 32-2j) -> 34 uniform steps. 384 items = grid, no queue.
#define C2 0.18033688011112042f   /* 0.125 * log2(e) */
#define THR 8.0f

__global__ __launch_bounds__(256, 2) void attn_flash_mfma(
    const unsigned short* __restrict__ qb,
    const unsigned short* __restrict__ kb,
    const unsigned short* __restrict__ vT,
    unsigned short* __restrict__ yatt)
{
    __shared__ unsigned short Ks[2][64 * 64];   // [k][d] swizzled
    __shared__ unsigned short Vs[2][64 * 64];   // [d][k] swizzled

    const int bid  = blockIdx.x;
    const int hint = bid & 7;            // XCD slot
    const int idx  = bid >> 3;           // 0..47
    const int bh   = hint * 6 + idx % 6;
    const int jp   = idx / 6;            // 0..7
    const int h = bh % HN, b = bh / HN;

    const int tid  = threadIdx.x;
    const int lane = tid & 63;
    const int wid  = tid >> 6;
    const int l15  = lane & 15;
    const int l4   = lane >> 4;

    bfrag onesf;
    #pragma unroll
    for (int j = 0; j < 8; ++j) onesf[j] = (short)0x3F80;   // bf16 1.0

    const unsigned short* kg = kb + (size_t)b * SEQ * BDIM + h * HDIM;
    const unsigned short* vg = vT + (size_t)bh * HDIM * SEQ;

    auto stage = [&](int bufi, int ktile) {
        const int k0 = ktile * 64;
        #pragma unroll
        for (int i = 0; i < 2; ++i) {
            const int row = wid * 16 + i * 8 + (lane >> 3);
            const int ck  = ((lane & 7) ^ (row & 7)) * 8;
            __builtin_amdgcn_global_load_lds(
                (const __attribute__((address_space(1))) void*)(kg + (size_t)(k0 + row) * BDIM + ck),
                (__attribute__((address_space(3))) void*)(&Ks[bufi][(wid * 16 + i * 8) * 64]),
                16, 0, 0);
            __builtin_amdgcn_global_load_lds(
                (const __attribute__((address_space(1))) void*)(vg + (size_t)row * SEQ + k0 + ck),
                (__attribute__((address_space(3))) void*)(&Vs[bufi][(wid * 16 + i * 8) * 64]),
                16, 0, 0);
        }
    };

    // softmax for one q-half: max-reduce, defer-max rescale, exp, P-dance.
    // Row-sum happens later via mfma(pf, ones) in the deferred cluster.
    auto softmax_dance = [&](f32x4* s, float& mm, pfu* pf, f32x4* acc, f32x4& accl) {
        float mx = s[0][0];
        #pragma unroll
        for (int cs = 0; cs < 4; ++cs)
            #pragma unroll
            for (int r = 0; r < 4; ++r) mx = fmaxf(mx, s[cs][r]);
        mx = redmax16(mx);
        mx = redmax32(mx);
        const float mx2 = mx * C2;

        if (!__all(mx2 <= mm + THR)) {
            const float mnew = fmaxf(mm, mx2);
            const float fac  = fexp2(mm - mnew);
            mm = mnew;
            #pragma unroll
            for (int r = 0; r < 4; ++r) {
                const float fr = __shfl(fac, (lane & 48) | (l4 * 4 + r));
                #pragma unroll
                for (int ds = 0; ds < 4; ++ds) acc[ds][r] *= fr;
                accl[r] *= fr;
            }
        }

        #pragma unroll
        for (int cs = 0; cs < 4; ++cs)
            #pragma unroll
            for (int r = 0; r < 4; ++r)
                s[cs][r] = fexp2(fmaf(s[cs][r], C2, -mm));

        unsigned pk[4][2];
        #pragma unroll
        for (int cs = 0; cs < 4; ++cs) {
            pk[cs][0] = cvt_pk_bf16(s[cs][0], s[cs][1]);
            pk[cs][1] = cvt_pk_bf16(s[cs][2], s[cs][3]);
        }
        #pragma unroll
        for (int ks = 0; ks < 2; ++ks)
            #pragma unroll
            for (int i = 0; i < 2; ++i) {
#if HAVE_PERMLANE
                auto r1 = __builtin_amdgcn_permlane32_swap(
                    pk[ks * 2][i], pk[ks * 2 + 1][i], false, false);
                auto r2 = __builtin_amdgcn_permlane16_swap(r1[0], r1[1], false, false);
                pf[ks].u[i]     = r2[0];
                pf[ks].u[2 + i] = r2[1];
#else
                const unsigned A  = pk[ks * 2][i];
                const unsigned B  = pk[ks * 2 + 1][i];
                const unsigned Ax = __shfl_xor(A, 32);
                const unsigned Bx = __shfl_xor(B, 32);
                const unsigned P1 = (l4 < 2) ? A : Bx;
                const unsigned P2 = (l4 < 2) ? Ax : B;
                const unsigned S1 = __shfl_xor(P1, 16);
                const unsigned S2 = __shfl_xor(P2, 16);
                pf[ks].u[i]     = (l4 & 1) ? S2 : P1;
                pf[ks].u[2 + i] = (l4 & 1) ? P2 : S1;
#endif
            }
    };

    #pragma unroll 1
    for (int seg = 0; seg < 2; ++seg) {
        const int p  = seg ? (15 - jp) : jp;
        const int q0 = p * 128;
        const int ktmax = 2 * p + 1;

        // Q fragments (B-operand), two q-halves 64 rows apart
        bfrag qf[2][2];
        {
            const unsigned short* qr0 =
                qb + (size_t)(b * SEQ + q0 + wid * 16 + l15) * BDIM + h * HDIM;
            qf[0][0] = *(const bfrag*)(qr0 + l4 * 8);
            qf[0][1] = *(const bfrag*)(qr0 + 32 + l4 * 8);
            const unsigned short* qr1 = qr0 + (size_t)64 * BDIM;
            qf[1][0] = *(const bfrag*)(qr1 + l4 * 8);
            qf[1][1] = *(const bfrag*)(qr1 + 32 + l4 * 8);
        }

        f32x4 acc0[4] = {}, acc1[4] = {};
        f32x4 accl0 = {}, accl1 = {};
        float m0v = -3.0e38f, m1v = -3.0e38f;

        pfu pf0[2], pf1[2];
        bfrag vr[2][4];
        #pragma unroll
        for (int ks = 0; ks < 2; ++ks) {
            #pragma unroll
            for (int i = 0; i < 4; ++i) { pf0[ks].u[i] = 0u; pf1[ks].u[i] = 0u; }
            #pragma unroll
            for (int ds = 0; ds < 4; ++ds)
                #pragma unroll
                for (int j = 0; j < 8; ++j) vr[ks][ds][j] = 0;
        }

        __syncthreads();          // protect K/V buffers from previous segment
        stage(0, 0);
        __syncthreads();

        int buf = 0;
        for (int kt = 0;;) {
            if (kt < ktmax) stage(buf ^ 1, kt + 1);   // async prefetch

            const unsigned short* Kb = Ks[buf];
            const unsigned short* Vb = Vs[buf];

            // ---- MFMA cluster: QK(kt) both halves + deferred PV/rowsum(kt-1)
            f32x4 s0[4] = {}, s1[4] = {};
            __builtin_amdgcn_s_setprio(1);
            #pragma unroll
            for (int ks = 0; ks < 2; ++ks) {
                #pragma unroll
                for (int cs = 0; cs < 4; ++cs) {
                    const int row = cs * 16 + l15;
                    const int ch  = (ks * 4 + l4) ^ (row & 7);
                    const bfrag kf = *(const bfrag*)(Kb + row * 64 + ch * 8);
                    s0[cs] = __builtin_amdgcn_mfma_f32_16x16x32_bf16(kf, qf[0][ks], s0[cs], 0, 0, 0);
                    s1[cs] = __builtin_amdgcn_mfma_f32_16x16x32_bf16(kf, qf[1][ks], s1[cs], 0, 0, 0);
                }
            }
            #pragma unroll
            for (int ks = 0; ks < 2; ++ks) {
                #pragma unroll
                for (int ds = 0; ds < 4; ++ds) {
                    acc0[ds] = __builtin_amdgcn_mfma_f32_16x16x32_bf16(pf0[ks].f, vr[ks][ds], acc0[ds], 0, 0, 0);
                    acc1[ds] = __builtin_amdgcn_mfma_f32_16x16x32_bf16(pf1[ks].f, vr[ks][ds], acc1[ds], 0, 0, 0);
                }
                accl0 = __builtin_amdgcn_mfma_f32_16x16x32_bf16(pf0[ks].f, onesf, accl0, 0, 0, 0);
                accl1 = __builtin_amdgcn_mfma_f32_16x16x32_bf16(pf1[ks].f, onesf, accl1, 0, 0, 0);
            }
            __builtin_amdgcn_s_setprio(0);

            // ---- refill V regs with tile kt ----
            #pragma unroll
            for (int ks = 0; ks < 2; ++ks)
                #pragma unroll
                for (int ds = 0; ds < 4; ++ds) {
                    const int vrow = ds * 16 + l15;
                    const int vch  = (ks * 4 + l4) ^ (vrow & 7);
                    vr[ks][ds] = *(const bfrag*)(Vb + vrow * 64 + vch * 8);
                }

            // ---- causal mask (only the last two K-tiles can clip) ----
            if (kt >= 2 * p) {
                const int qg = q0 + wid * 16 + l15;
                #pragma unroll
                for (int cs = 0; cs < 4; ++cs)
                    #pragma unroll
                    for (int r = 0; r < 4; ++r) {
                        const int kgl = kt * 64 + cs * 16 + l4 * 4 + r;
                        if (kgl > qg)      s0[cs][r] = -3.0e38f;
                        if (kgl > qg + 64) s1[cs][r] = -3.0e38f;
                    }
            }

            softmax_dance(s0, m0v, pf0, acc0, accl0);
            softmax_dance(s1, m1v, pf1, acc1, accl1);

            if (kt == ktmax) break;
            __syncthreads();      // drains own gload_lds + all waves done
            buf ^= 1; ++kt;
        }

        // ---- epilogue: deferred PV + rowsum of final tile ----
        #pragma unroll
        for (int ks = 0; ks < 2; ++ks) {
            #pragma unroll
            for (int ds = 0; ds < 4; ++ds) {
                acc0[ds] = __builtin_amdgcn_mfma_f32_16x16x32_bf16(pf0[ks].f, vr[ks][ds], acc0[ds], 0, 0, 0);
                acc1[ds] = __builtin_amdgcn_mfma_f32_16x16x32_bf16(pf1[ks].f, vr[ks][ds], acc1[ds], 0, 0, 0);
            }
            accl0 = __builtin_amdgcn_mfma_f32_16x16x32_bf16(pf0[ks].f, onesf, accl0, 0, 0, 0);
            accl1 = __builtin_amdgcn_mfma_f32_16x16x32_bf16(pf1[ks].f, onesf, accl1, 0, 0, 0);
        }

        // ---- normalize + store both halves (accl rows match acc rows) ----
        #pragma unroll
        for (int r = 0; r < 4; ++r) {
            const float iv0 = 1.f / accl0[r];
            const float iv1 = 1.f / accl1[r];
            unsigned short* o0 =
                yatt + (size_t)(b * SEQ + q0 + wid * 16 + l4 * 4 + r) * BDIM + h * HDIM;
            unsigned short* o1 = o0 + (size_t)64 * BDIM;
            #pragma unroll
            for (int ds = 0; ds < 4; ++ds) {
                o0[ds * 16 + l15] = f2bf(acc0[ds][r] * iv0);
                o1[ds * 16 + l15] = f2bf(acc1[ds][r] * iv1);
            }
        }
    }
}

// ---------------- launch -----------------------------------------------------
extern "C" void kernel_launch(void* const* d_in, const int* in_sizes, int n_in,
                              void* d_out, int out_size, void* d_ws, size_t ws_size,
                              hipStream_t stream)
{
    const float* x      = (const float*)d_in[0];
    const float* w_qkv  = (const float*)d_in[1];
    const float* b_qkv  = (const float*)d_in[2];
    const float* w_proj = (const float*)d_in[3];
    const float* b_proj = (const float*)d_in[4];
    float* out = (float*)d_out;

    unsigned short* xb   = (unsigned short*)d_ws;                 // [8192][768]
    unsigned short* qb   = xb  + (size_t)MTOT * BDIM;             // [8192][768]
    unsigned short* kbuf = qb  + (size_t)MTOT * BDIM;             // [8192][768]
    unsigned short* vT   = kbuf + (size_t)MTOT * BDIM;            // [4*768][2048]
    unsigned short* yatt = vT  + (size_t)MTOT * BDIM;             // [8192][768]
    unsigned short* wqT  = yatt + (size_t)MTOT * BDIM;            // [2304][768]
    unsigned short* wpT  = wqT + (size_t)3 * BDIM * BDIM;         // [768][768]

    // prep
    conv_f32_bf16<<<(MTOT * BDIM / 8 + 255) / 256, 256, 0, stream>>>(
        x, xb, MTOT * BDIM / 8);
    transpose_f32_bf16<<<dim3(3 * BDIM / 64, BDIM / 64), 256, 0, stream>>>(
        w_qkv, wqT, BDIM, 3 * BDIM);
    transpose_f32_bf16<<<dim3(BDIM / 64, BDIM / 64), 256, 0, stream>>>(
        w_proj, wpT, BDIM, BDIM);

    // qkv GEMM with routed epilogue (Q->qb, K->kb, V->vT transposed)
    gemm_qkv<<<dim3(3 * BDIM / 128, MTOT / 128), 256, 0, stream>>>(
        xb, wqT, b_qkv, qb, kbuf, vT);

    // flash attention (static uniform causal-paired items)
    attn_flash_mfma<<<dim3(384), 256, 0, stream>>>(qb, kbuf, vT, yatt);

    // out = yatt @ w_proj + b_proj   (fp32 out, 64x128 tiles)
    gemm_proj<<<dim3(BDIM / 128, MTOT / 64), 256, 0, stream>>>(
        yatt, wpT, b_proj, out);
}

// Round 14
// 137.554 us; speedup vs baseline: 1.7342x; 1.0205x over previous
//
#include <hip/hip_runtime.h>
#include <hip/hip_bf16.h>
#include <cstdint>

#define BDIM 768
#define HN 12
#define HDIM 64
#define SEQ 2048
#define BATCH 4
#define MTOT (BATCH * SEQ)     // 8192

typedef __attribute__((ext_vector_type(8))) short bfrag;   // 8 bf16 (4 VGPR)
typedef __attribute__((ext_vector_type(4))) float f32x4;

union pfu { bfrag f; unsigned u[4]; };

static __device__ __forceinline__ unsigned short f2bf(float f) {
    union { float f; unsigned u; } v; v.f = f;
    unsigned r = v.u + 0x7FFF + ((v.u >> 16) & 1);   // RNE
    return (unsigned short)(r >> 16);
}

static __device__ __forceinline__ float fexp2(float x) {
    float r; asm("v_exp_f32 %0, %1" : "=v"(r) : "v"(x)); return r;
}

static __device__ __forceinline__ unsigned cvt_pk_bf16(float lo, float hi) {
    unsigned r;
    asm("v_cvt_pk_bf16_f32 %0, %1, %2" : "=v"(r) : "v"(lo), "v"(hi));
    return r;
}

// ---- cross-lane helpers: permlane swaps (VALU) with shfl fallback ----------
#if __has_builtin(__builtin_amdgcn_permlane32_swap) && __has_builtin(__builtin_amdgcn_permlane16_swap)
#define HAVE_PERMLANE 1
#else
#define HAVE_PERMLANE 0
#endif

static __device__ __forceinline__ float redmax16(float x) {
#if HAVE_PERMLANE
    union { float f; unsigned u; } a; a.f = x;
    auto r = __builtin_amdgcn_permlane16_swap(a.u, a.u, false, false);
    union { unsigned u; float f; } p, q; p.u = r[0]; q.u = r[1];
    return fmaxf(p.f, q.f);
#else
    return fmaxf(x, __shfl_xor(x, 16));
#endif
}

static __device__ __forceinline__ float redmax32(float x) {
#if HAVE_PERMLANE
    union { float f; unsigned u; } a; a.f = x;
    auto r = __builtin_amdgcn_permlane32_swap(a.u, a.u, false, false);
    union { unsigned u; float f; } p, q; p.u = r[0]; q.u = r[1];
    return fmaxf(p.f, q.f);
#else
    return fmaxf(x, __shfl_xor(x, 32));
#endif
}

// ---------------- prep: fp32 -> bf16 flat convert (+ queue init) -------------
__global__ __launch_bounds__(256) void conv_f32_bf16(
    const float* __restrict__ in, unsigned short* __restrict__ out, int n8,
    int* __restrict__ qctr)
{
    if (blockIdx.x == 0 && threadIdx.x < 8) qctr[threadIdx.x] = 0;
    const int i = blockIdx.x * 256 + threadIdx.x;
    if (i >= n8) return;
    const float4 a = ((const float4*)in)[i * 2];
    const float4 b = ((const float4*)in)[i * 2 + 1];
    bfrag o;
    o[0] = f2bf(a.x); o[1] = f2bf(a.y); o[2] = f2bf(a.z); o[3] = f2bf(a.w);
    o[4] = f2bf(b.x); o[5] = f2bf(b.y); o[6] = f2bf(b.z); o[7] = f2bf(b.w);
    ((bfrag*)out)[i] = o;
}

// ---------------- prep: [R][C] fp32 -> [C][R] bf16 transpose ----------------
__global__ __launch_bounds__(256) void transpose_f32_bf16(
    const float* __restrict__ in, unsigned short* __restrict__ out, int R, int C)
{
    __shared__ unsigned short t[64][72];
    const int tid = threadIdx.x;
    const int c0 = blockIdx.x * 64, r0 = blockIdx.y * 64;
    #pragma unroll
    for (int i = 0; i < 4; ++i) {
        const int r = (tid >> 4) + i * 16;
        const int c = (tid & 15) * 4;
        const float4 v = *(const float4*)&in[(size_t)(r0 + r) * C + c0 + c];
        t[c + 0][r] = f2bf(v.x);
        t[c + 1][r] = f2bf(v.y);
        t[c + 2][r] = f2bf(v.z);
        t[c + 3][r] = f2bf(v.w);
    }
    __syncthreads();
    #pragma unroll
    for (int i = 0; i < 2; ++i) {
        const int c = (tid >> 3) + i * 32;
        const int r = (tid & 7) * 8;
        *(bfrag*)&out[(size_t)(c0 + c) * R + r0 + r] = *(const bfrag*)&t[c][r];
    }
}

// ---------------- GEMM1: qkv = x @ wqT^T + b, routed to qb/kb/vT ------------
__global__ __launch_bounds__(256) void gemm_qkv(
    const unsigned short* __restrict__ A,
    const unsigned short* __restrict__ Bt,
    const float* __restrict__ bias,
    unsigned short* __restrict__ qb,
    unsigned short* __restrict__ kb,
    unsigned short* __restrict__ vTt)
{
    __shared__ unsigned short As[128 * 64];
    __shared__ unsigned short Bs[128 * 64];

    const int tid  = threadIdx.x;
    const int lane = tid & 63;
    const int wid  = tid >> 6;
    const int l15  = lane & 15;
    const int l4   = lane >> 4;

    // bijective XCD swizzle (nwg = 18*64 = 1152, 1152 % 8 == 0)
    const int nwg  = (int)(gridDim.x * gridDim.y);
    const int flat = (int)(blockIdx.y * gridDim.x + blockIdx.x);
    const int swz  = (flat & 7) * (nwg >> 3) + (flat >> 3);
    const int m0 = (swz / (int)gridDim.x) * 128;
    const int n0 = (swz % (int)gridDim.x) * 128;

    const int wm = (wid >> 1) * 64;
    const int wn = (wid & 1) * 64;

    f32x4 acc[4][4] = {};

    for (int k0 = 0; k0 < BDIM; k0 += 64) {
        __syncthreads();
        #pragma unroll
        for (int i = 0; i < 4; ++i) {
            const int row = wid * 32 + i * 8 + (lane >> 3);
            const int ck  = (((lane & 7) ^ (row & 7)) * 8);
            __builtin_amdgcn_global_load_lds(
                (const __attribute__((address_space(1))) void*)(A + (size_t)(m0 + row) * BDIM + k0 + ck),
                (__attribute__((address_space(3))) void*)(As + (wid * 4 + i) * 512),
                16, 0, 0);
            __builtin_amdgcn_global_load_lds(
                (const __attribute__((address_space(1))) void*)(Bt + (size_t)(n0 + row) * BDIM + k0 + ck),
                (__attribute__((address_space(3))) void*)(Bs + (wid * 4 + i) * 512),
                16, 0, 0);
        }
        __syncthreads();

        #pragma unroll
        for (int ks = 0; ks < 2; ++ks) {
            bfrag af[4], bfv[4];
            #pragma unroll
            for (int mi = 0; mi < 4; ++mi) {
                const int row = wm + mi * 16 + l15;
                const int ch  = (ks * 4 + l4) ^ (row & 7);
                af[mi] = *(const bfrag*)(As + row * 64 + ch * 8);
            }
            #pragma unroll
            for (int ni = 0; ni < 4; ++ni) {
                const int row = wn + ni * 16 + l15;
                const int ch  = (ks * 4 + l4) ^ (row & 7);
                bfv[ni] = *(const bfrag*)(Bs + row * 64 + ch * 8);
            }
            #pragma unroll
            for (int mi = 0; mi < 4; ++mi)
                #pragma unroll
                for (int ni = 0; ni < 4; ++ni)
                    acc[mi][ni] = __builtin_amdgcn_mfma_f32_16x16x32_bf16(
                        af[mi], bfv[ni], acc[mi][ni], 0, 0, 0);
        }
    }

    const int nb = n0 + wn;
    if (nb < 1536) {
        unsigned short* dst = (nb < 768) ? qb : kb;
        const int coff = (nb < 768) ? 0 : 768;
        #pragma unroll
        for (int mi = 0; mi < 4; ++mi)
            #pragma unroll
            for (int ni = 0; ni < 4; ++ni) {
                const int n = nb + ni * 16 + l15;
                const float bv = bias[n];
                #pragma unroll
                for (int r = 0; r < 4; ++r) {
                    const int m = m0 + wm + mi * 16 + l4 * 4 + r;
                    dst[(size_t)m * BDIM + (n - coff)] = f2bf(acc[mi][ni][r] + bv);
                }
            }
    } else {
        // V block: write transposed into vT[(b*768 + n-1536)][s]
        #pragma unroll
        for (int mi = 0; mi < 4; ++mi)
            #pragma unroll
            for (int ni = 0; ni < 4; ++ni) {
                const int n = nb + ni * 16 + l15;
                const float bv = bias[n];
                const size_t vrow = (size_t)(m0 >> 11) * 768 + (n - 1536);
                const int mbase = m0 + wm + mi * 16 + l4 * 4;
                const int scol = mbase & (SEQ - 1);
                uint2 u2;
                u2.x = (unsigned)f2bf(acc[mi][ni][0] + bv)
                     | ((unsigned)f2bf(acc[mi][ni][1] + bv) << 16);
                u2.y = (unsigned)f2bf(acc[mi][ni][2] + bv)
                     | ((unsigned)f2bf(acc[mi][ni][3] + bv) << 16);
                *(uint2*)(vTt + vrow * SEQ + scol) = u2;
            }
    }
}

// ---------------- GEMM2: out = yatt @ wpT^T + b (fp32 out), 64x128 tiles ----
__global__ __launch_bounds__(256) void gemm_proj(
    const unsigned short* __restrict__ A,   // [8192][768] bf16
    const unsigned short* __restrict__ Bt,  // [768][768] bf16
    const float* __restrict__ bias,
    float* __restrict__ C)
{
    __shared__ unsigned short As[64 * 64];    // 64 M-rows x 64 k
    __shared__ unsigned short Bs[128 * 64];   // 128 N-rows x 64 k

    const int tid  = threadIdx.x;
    const int lane = tid & 63;
    const int wid  = tid >> 6;
    const int l15  = lane & 15;
    const int l4   = lane >> 4;

    // bijective XCD swizzle (nwg = 6*128 = 768, 768 % 8 == 0)
    const int nwg  = (int)(gridDim.x * gridDim.y);
    const int flat = (int)(blockIdx.y * gridDim.x + blockIdx.x);
    const int swz  = (flat & 7) * (nwg >> 3) + (flat >> 3);
    const int m0 = (swz / (int)gridDim.x) * 64;
    const int n0 = (swz % (int)gridDim.x) * 128;

    const int wm = (wid >> 1) * 32;    // 2 m-sub of 32 rows
    const int wn = (wid & 1) * 64;

    f32x4 acc[2][4] = {};

    for (int k0 = 0; k0 < BDIM; k0 += 64) {
        __syncthreads();
        #pragma unroll
        for (int i = 0; i < 2; ++i) {   // A: 64 rows, 2 instr/wave
            const int row = wid * 16 + i * 8 + (lane >> 3);
            const int ck  = (((lane & 7) ^ (row & 7)) * 8);
            __builtin_amdgcn_global_load_lds(
                (const __attribute__((address_space(1))) void*)(A + (size_t)(m0 + row) * BDIM + k0 + ck),
                (__attribute__((address_space(3))) void*)(As + (wid * 16 + i * 8) * 64),
                16, 0, 0);
        }
        #pragma unroll
        for (int i = 0; i < 4; ++i) {   // B: 128 rows, 4 instr/wave
            const int row = wid * 32 + i * 8 + (lane >> 3);
            const int ck  = (((lane & 7) ^ (row & 7)) * 8);
            __builtin_amdgcn_global_load_lds(
                (const __attribute__((address_space(1))) void*)(Bt + (size_t)(n0 + row) * BDIM + k0 + ck),
                (__attribute__((address_space(3))) void*)(Bs + (wid * 32 + i * 8) * 64),
                16, 0, 0);
        }
        __syncthreads();

        #pragma unroll
        for (int ks = 0; ks < 2; ++ks) {
            bfrag af[2], bfv[4];
            #pragma unroll
            for (int mi = 0; mi < 2; ++mi) {
                const int row = wm + mi * 16 + l15;
                const int ch  = (ks * 4 + l4) ^ (row & 7);
                af[mi] = *(const bfrag*)(As + row * 64 + ch * 8);
            }
            #pragma unroll
            for (int ni = 0; ni < 4; ++ni) {
                const int row = wn + ni * 16 + l15;
                const int ch  = (ks * 4 + l4) ^ (row & 7);
                bfv[ni] = *(const bfrag*)(Bs + row * 64 + ch * 8);
            }
            #pragma unroll
            for (int mi = 0; mi < 2; ++mi)
                #pragma unroll
                for (int ni = 0; ni < 4; ++ni)
                    acc[mi][ni] = __builtin_amdgcn_mfma_f32_16x16x32_bf16(
                        af[mi], bfv[ni], acc[mi][ni], 0, 0, 0);
        }
    }

    #pragma unroll
    for (int mi = 0; mi < 2; ++mi)
        #pragma unroll
        for (int ni = 0; ni < 4; ++ni) {
            const int n = n0 + wn + ni * 16 + l15;
            const float bv = bias[n];
            #pragma unroll
            for (int r = 0; r < 4; ++r) {
                const int m = m0 + wm + mi * 16 + l4 * 4 + r;
                C[(size_t)m * BDIM + n] = acc[mi][ni][r] + bv;
            }
        }
}

// ---------------- MFMA flash attention: dual q-half, 3-buffer pipeline ------
// Item = (bh, p): q-rows [p*128, p*128+128), K-tiles 0..2p+1. 768 items,
// longest-first, 8 queues x 96; grid 512 (2 blocks/CU). Counted-vmcnt
// barriers: stage tile t+2 at step t; never drain vmcnt to 0 mid-loop.
#define C2 0.18033688011112042f   /* 0.125 * log2(e) */
#define THR 8.0f

__global__ __launch_bounds__(256, 2) void attn_flash_mfma(
    const unsigned short* __restrict__ qb,
    const unsigned short* __restrict__ kb,
    const unsigned short* __restrict__ vT,
    unsigned short* __restrict__ yatt,
    int* __restrict__ qctr)
{
    __shared__ unsigned short Ks[3][64 * 64];   // [k][d] swizzled
    __shared__ unsigned short Vs[3][64 * 64];   // [d][k] swizzled

    const int hint = blockIdx.x & 7;
    const int tid  = threadIdx.x;
    const int lane = tid & 63;
    const int wid  = tid >> 6;
    const int l15  = lane & 15;
    const int l4   = lane >> 4;

    bfrag onesf;
    #pragma unroll
    for (int j = 0; j < 8; ++j) onesf[j] = (short)0x3F80;   // bf16 1.0

    for (;;) {
        __syncthreads();                       // prev item's compute done
        if (tid == 0) *(int*)&Ks[0][0] = atomicAdd(&qctr[hint], 1);
        __syncthreads();
        const int it = *(const int*)&Ks[0][0];
        if (it >= 96) break;
        __syncthreads();                       // all read `it` before staging

        const int bh = hint * 6 + (it % 6);
        const int p  = 15 - (it / 6);          // longest first
        const int h = bh % HN, b = bh / HN;
        const int q0 = p * 128;
        const int ktmax = 2 * p + 1;

        const unsigned short* kg = kb + (size_t)b * SEQ * BDIM + h * HDIM;
        const unsigned short* vg = vT + (size_t)bh * HDIM * SEQ;

        // Q fragments (B-operand), two q-halves 64 rows apart
        bfrag qf[2][2];
        {
            const unsigned short* qr0 =
                qb + (size_t)(b * SEQ + q0 + wid * 16 + l15) * BDIM + h * HDIM;
            qf[0][0] = *(const bfrag*)(qr0 + l4 * 8);
            qf[0][1] = *(const bfrag*)(qr0 + 32 + l4 * 8);
            const unsigned short* qr1 = qr0 + (size_t)64 * BDIM;
            qf[1][0] = *(const bfrag*)(qr1 + l4 * 8);
            qf[1][1] = *(const bfrag*)(qr1 + 32 + l4 * 8);
        }

        f32x4 acc0[4] = {}, acc1[4] = {};
        f32x4 accl0 = {}, accl1 = {};
        float m0v = -3.0e38f, m1v = -3.0e38f;

        pfu pf0[2], pf1[2];
        bfrag vr[2][4];
        #pragma unroll
        for (int ks = 0; ks < 2; ++ks) {
            #pragma unroll
            for (int i = 0; i < 4; ++i) { pf0[ks].u[i] = 0u; pf1[ks].u[i] = 0u; }
            #pragma unroll
            for (int ds = 0; ds < 4; ++ds)
                #pragma unroll
                for (int j = 0; j < 8; ++j) vr[ks][ds][j] = 0;
        }

        auto stage = [&](int bufi, int ktile) {
            const int k0 = ktile * 64;
            #pragma unroll
            for (int i = 0; i < 2; ++i) {
                const int row = wid * 16 + i * 8 + (lane >> 3);
                const int ck  = ((lane & 7) ^ (row & 7)) * 8;
                __builtin_amdgcn_global_load_lds(
                    (const __attribute__((address_space(1))) void*)(kg + (size_t)(k0 + row) * BDIM + ck),
                    (__attribute__((address_space(3))) void*)(&Ks[bufi][(wid * 16 + i * 8) * 64]),
                    16, 0, 0);
                __builtin_amdgcn_global_load_lds(
                    (const __attribute__((address_space(1))) void*)(vg + (size_t)row * SEQ + k0 + ck),
                    (__attribute__((address_space(3))) void*)(&Vs[bufi][(wid * 16 + i * 8) * 64]),
                    16, 0, 0);
            }
        };

        // softmax for one q-half: max-reduce, defer-max rescale, exp, P-dance.
        auto softmax_dance = [&](f32x4* s, float& mm, pfu* pf, f32x4* acc, f32x4& accl) {
            float mx = s[0][0];
            #pragma unroll
            for (int cs = 0; cs < 4; ++cs)
                #pragma unroll
                for (int r = 0; r < 4; ++r) mx = fmaxf(mx, s[cs][r]);
            mx = redmax16(mx);
            mx = redmax32(mx);
            const float mx2 = mx * C2;

            if (!__all(mx2 <= mm + THR)) {
                const float mnew = fmaxf(mm, mx2);
                const float fac  = fexp2(mm - mnew);
                mm = mnew;
                #pragma unroll
                for (int r = 0; r < 4; ++r) {
                    const float fr = __shfl(fac, (lane & 48) | (l4 * 4 + r));
                    #pragma unroll
                    for (int ds = 0; ds < 4; ++ds) acc[ds][r] *= fr;
                    accl[r] *= fr;
                }
            }

            #pragma unroll
            for (int cs = 0; cs < 4; ++cs)
                #pragma unroll
                for (int r = 0; r < 4; ++r)
                    s[cs][r] = fexp2(fmaf(s[cs][r], C2, -mm));

            unsigned pk[4][2];
            #pragma unroll
            for (int cs = 0; cs < 4; ++cs) {
                pk[cs][0] = cvt_pk_bf16(s[cs][0], s[cs][1]);
                pk[cs][1] = cvt_pk_bf16(s[cs][2], s[cs][3]);
            }
            #pragma unroll
            for (int ks = 0; ks < 2; ++ks)
                #pragma unroll
                for (int i = 0; i < 2; ++i) {
#if HAVE_PERMLANE
                    auto r1 = __builtin_amdgcn_permlane32_swap(
                        pk[ks * 2][i], pk[ks * 2 + 1][i], false, false);
                    auto r2 = __builtin_amdgcn_permlane16_swap(r1[0], r1[1], false, false);
                    pf[ks].u[i]     = r2[0];
                    pf[ks].u[2 + i] = r2[1];
#else
                    const unsigned A  = pk[ks * 2][i];
                    const unsigned B  = pk[ks * 2 + 1][i];
                    const unsigned Ax = __shfl_xor(A, 32);
                    const unsigned Bx = __shfl_xor(B, 32);
                    const unsigned P1 = (l4 < 2) ? A : Bx;
                    const unsigned P2 = (l4 < 2) ? Ax : B;
                    const unsigned S1 = __shfl_xor(P1, 16);
                    const unsigned S2 = __shfl_xor(P2, 16);
                    pf[ks].u[i]     = (l4 & 1) ? S2 : P1;
                    pf[ks].u[2 + i] = (l4 & 1) ? P2 : S1;
#endif
                }
        };

        // prologue: stage tiles 0 and 1 (ktmax >= 1 always)
        stage(0, 0);
        stage(1, 1);
        // drain tile-0 loads (keep tile-1's 4 in flight), then barrier
        asm volatile("s_waitcnt vmcnt(4) lgkmcnt(0)\ns_barrier" ::: "memory");

        int kt = 0;
        for (;;) {
            const int cb = kt % 3;
            const bool willstage = (kt + 2 <= ktmax);
            if (willstage) stage((kt + 2) % 3, kt + 2);   // deep prefetch

            const unsigned short* Kb = Ks[cb];
            const unsigned short* Vb = Vs[cb];

            // ---- MFMA cluster: QK(kt) both halves + deferred PV/rowsum(kt-1)
            f32x4 s0[4] = {}, s1[4] = {};
            __builtin_amdgcn_s_setprio(1);
            #pragma unroll
            for (int ks = 0; ks < 2; ++ks) {
                #pragma unroll
                for (int cs = 0; cs < 4; ++cs) {
                    const int row = cs * 16 + l15;
                    const int ch  = (ks * 4 + l4) ^ (row & 7);
                    const bfrag kf = *(const bfrag*)(Kb + row * 64 + ch * 8);
                    s0[cs] = __builtin_amdgcn_mfma_f32_16x16x32_bf16(kf, qf[0][ks], s0[cs], 0, 0, 0);
                    s1[cs] = __builtin_amdgcn_mfma_f32_16x16x32_bf16(kf, qf[1][ks], s1[cs], 0, 0, 0);
                }
            }
            #pragma unroll
            for (int ks = 0; ks < 2; ++ks) {
                #pragma unroll
                for (int ds = 0; ds < 4; ++ds) {
                    acc0[ds] = __builtin_amdgcn_mfma_f32_16x16x32_bf16(pf0[ks].f, vr[ks][ds], acc0[ds], 0, 0, 0);
                    acc1[ds] = __builtin_amdgcn_mfma_f32_16x16x32_bf16(pf1[ks].f, vr[ks][ds], acc1[ds], 0, 0, 0);
                }
                accl0 = __builtin_amdgcn_mfma_f32_16x16x32_bf16(pf0[ks].f, onesf, accl0, 0, 0, 0);
                accl1 = __builtin_amdgcn_mfma_f32_16x16x32_bf16(pf1[ks].f, onesf, accl1, 0, 0, 0);
            }
            __builtin_amdgcn_s_setprio(0);

            // ---- refill V regs with tile kt ----
            #pragma unroll
            for (int ks = 0; ks < 2; ++ks)
                #pragma unroll
                for (int ds = 0; ds < 4; ++ds) {
                    const int vrow = ds * 16 + l15;
                    const int vch  = (ks * 4 + l4) ^ (vrow & 7);
                    vr[ks][ds] = *(const bfrag*)(Vb + vrow * 64 + vch * 8);
                }

            // ---- causal mask (only the last two K-tiles can clip) ----
            if (kt >= 2 * p) {
                const int qg = q0 + wid * 16 + l15;
                #pragma unroll
                for (int cs = 0; cs < 4; ++cs)
                    #pragma unroll
                    for (int r = 0; r < 4; ++r) {
                        const int kgl = kt * 64 + cs * 16 + l4 * 4 + r;
                        if (kgl > qg)      s0[cs][r] = -3.0e38f;
                        if (kgl > qg + 64) s1[cs][r] = -3.0e38f;
                    }
            }

            softmax_dance(s0, m0v, pf0, acc0, accl0);
            softmax_dance(s1, m1v, pf1, acc1, accl1);

            if (kt == ktmax) break;
            // counted-vmcnt barrier: drain stage(kt+1) (oldest 4), keep
            // stage(kt+2)'s 4 in flight if issued; lgkmcnt protects V refill.
            if (willstage) {
                asm volatile("s_waitcnt vmcnt(4) lgkmcnt(0)\ns_barrier" ::: "memory");
            } else {
                asm volatile("s_waitcnt vmcnt(0) lgkmcnt(0)\ns_barrier" ::: "memory");
            }
            ++kt;
        }

        // ---- epilogue: deferred PV + rowsum of final tile ----
        #pragma unroll
        for (int ks = 0; ks < 2; ++ks) {
            #pragma unroll
            for (int ds = 0; ds < 4; ++ds) {
                acc0[ds] = __builtin_amdgcn_mfma_f32_16x16x32_bf16(pf0[ks].f, vr[ks][ds], acc0[ds], 0, 0, 0);
                acc1[ds] = __builtin_amdgcn_mfma_f32_16x16x32_bf16(pf1[ks].f, vr[ks][ds], acc1[ds], 0, 0, 0);
            }
            accl0 = __builtin_amdgcn_mfma_f32_16x16x32_bf16(pf0[ks].f, onesf, accl0, 0, 0, 0);
            accl1 = __builtin_amdgcn_mfma_f32_16x16x32_bf16(pf1[ks].f, onesf, accl1, 0, 0, 0);
        }

        // ---- normalize + store both halves (accl rows match acc rows) ----
        #pragma unroll
        for (int r = 0; r < 4; ++r) {
            const float iv0 = 1.f / accl0[r];
            const float iv1 = 1.f / accl1[r];
            unsigned short* o0 =
                yatt + (size_t)(b * SEQ + q0 + wid * 16 + l4 * 4 + r) * BDIM + h * HDIM;
            unsigned short* o1 = o0 + (size_t)64 * BDIM;
            #pragma unroll
            for (int ds = 0; ds < 4; ++ds) {
                o0[ds * 16 + l15] = f2bf(acc0[ds][r] * iv0);
                o1[ds * 16 + l15] = f2bf(acc1[ds][r] * iv1);
            }
        }
    }
}

// ---------------- launch -----------------------------------------------------
extern "C" void kernel_launch(void* const* d_in, const int* in_sizes, int n_in,
                              void* d_out, int out_size, void* d_ws, size_t ws_size,
                              hipStream_t stream)
{
    const float* x      = (const float*)d_in[0];
    const float* w_qkv  = (const float*)d_in[1];
    const float* b_qkv  = (const float*)d_in[2];
    const float* w_proj = (const float*)d_in[3];
    const float* b_proj = (const float*)d_in[4];
    float* out = (float*)d_out;

    unsigned short* xb   = (unsigned short*)d_ws;                 // [8192][768]
    unsigned short* qb   = xb  + (size_t)MTOT * BDIM;             // [8192][768]
    unsigned short* kbuf = qb  + (size_t)MTOT * BDIM;             // [8192][768]
    unsigned short* vT   = kbuf + (size_t)MTOT * BDIM;            // [4*768][2048]
    unsigned short* yatt = vT  + (size_t)MTOT * BDIM;             // [8192][768]
    unsigned short* wqT  = yatt + (size_t)MTOT * BDIM;            // [2304][768]
    unsigned short* wpT  = wqT + (size_t)3 * BDIM * BDIM;         // [768][768]
    int*            qctr = (int*)(wpT + (size_t)BDIM * BDIM);     // [8]

    // prep
    conv_f32_bf16<<<(MTOT * BDIM / 8 + 255) / 256, 256, 0, stream>>>(
        x, xb, MTOT * BDIM / 8, qctr);
    transpose_f32_bf16<<<dim3(3 * BDIM / 64, BDIM / 64), 256, 0, stream>>>(
        w_qkv, wqT, BDIM, 3 * BDIM);
    transpose_f32_bf16<<<dim3(BDIM / 64, BDIM / 64), 256, 0, stream>>>(
        w_proj, wpT, BDIM, BDIM);

    // qkv GEMM with routed epilogue (Q->qb, K->kb, V->vT transposed)
    gemm_qkv<<<dim3(3 * BDIM / 128, MTOT / 128), 256, 0, stream>>>(
        xb, wqT, b_qkv, qb, kbuf, vT);

    // flash attention (queue, 2 blocks/CU, 3-buffer counted-vmcnt pipeline)
    attn_flash_mfma<<<dim3(512), 256, 0, stream>>>(qb, kbuf, vT, yatt, qctr);

    // out = yatt @ w_proj + b_proj   (fp32 out, 64x128 tiles)
    gemm_proj<<<dim3(BDIM / 128, MTOT / 64), 256, 0, stream>>>(
        yatt, wpT, b_proj, out);
}